// Round 10
// baseline (1070.452 us; speedup 1.0000x reference)
//
#include <hip/hip_runtime.h>
#include <math.h>

// ---------------------------------------------------------------------------
// Problem constants
constexpr int Bn  = 2;
constexpr int C   = 256;
constexpr int H   = 256;
constexpr int W   = 256;
constexpr int HW  = H * W;          // 65536
constexpr size_t CHW = (size_t)C * HW;

typedef __bf16 bf16x8 __attribute__((ext_vector_type(8)));
typedef float  f32x4  __attribute__((ext_vector_type(4)));

// fp32 -> bf16 round-to-nearest-even
__device__ __forceinline__ unsigned short f2bf(float f) {
    unsigned int u = __float_as_uint(f);
    u += 0x7fffu + ((u >> 16) & 1u);
    return (unsigned short)(u >> 16);
}
__device__ __forceinline__ float bf2f(unsigned short h) {
    return __uint_as_float(((unsigned int)h) << 16);
}
// two bf16 packed in a uint -> floats (hi needs only a mask)
__device__ __forceinline__ float bflo(unsigned int u) { return __uint_as_float(u << 16); }
__device__ __forceinline__ float bfhi(unsigned int u) { return __uint_as_float(u & 0xffff0000u); }

__device__ __forceinline__ bf16x8 u2b(uint4 u) {
    union { uint4 a; bf16x8 b; } c; c.a = u; return c.b;
}

// async global->LDS, 16B per lane; LDS dest = uniform base + lane*16
__device__ __forceinline__ void gld_lds16(const void* g, void* lds) {
    __builtin_amdgcn_global_load_lds(
        (const __attribute__((address_space(1))) unsigned int*)g,
        (__attribute__((address_space(3))) unsigned int*)lds, 16, 0, 0);
}

// XCD-aware bijective swizzle for 2048-block grids (2048 % 8 == 0)
__device__ __forceinline__ int swz2048(int bid) {
    return ((bid & 7) << 8) | (bid >> 3);
}

// ---------------------------------------------------------------------------
// packx: x fp32 NCHW -> bf16 NHWC.  Tile 64c x 64px via LDS transpose.
// grid = (2*65536/64) * 4 = 8192 blocks
// ---------------------------------------------------------------------------
__global__ __launch_bounds__(256) void packx_k(
    const float* __restrict__ x, unsigned short* __restrict__ xT)
{
    __shared__ float tl[64][65];
    const int id = blockIdx.x;
    const int ct = id & 3;
    const size_t px0 = (size_t)(id >> 2) * 64;   // global pixel (incl batch)
    const int b  = (int)(px0 >> 16);
    const int hw = (int)(px0 & 65535);
    const int c0 = ct * 64;
    const int t  = threadIdx.x;

    {   // load: thread (cl, pseg): 16 px of channel cl
        const int cl = t >> 2, pseg = t & 3;
        const float* src = x + ((size_t)(b * C + c0 + cl)) * HW + hw + pseg * 16;
#pragma unroll
        for (int i = 0; i < 4; i++) {
            float4 v = *(const float4*)(src + i * 4);
            tl[cl][pseg * 16 + i * 4 + 0] = v.x;
            tl[cl][pseg * 16 + i * 4 + 1] = v.y;
            tl[cl][pseg * 16 + i * 4 + 2] = v.z;
            tl[cl][pseg * 16 + i * 4 + 3] = v.w;
        }
    }
    __syncthreads();
    {   // store: thread (pl, csec): 16 channels of pixel pl, contiguous in NHWC
        const int pl = t >> 2, csec = t & 3;
        __attribute__((aligned(16))) unsigned short rv[16];
#pragma unroll
        for (int j = 0; j < 16; j++) rv[j] = f2bf(tl[csec * 16 + j][pl]);
        unsigned short* dst = xT + (px0 + pl) * C + c0 + csec * 16;
        *(uint4*)dst       = *(const uint4*)&rv[0];
        *(uint4*)(dst + 8) = *(const uint4*)&rv[8];
    }
}

// ---------------------------------------------------------------------------
// pack weights into the LDS image the GEMM stages:
// layout [taps][oct(2)][icc(8)][ocl(128)][kslot(32)], with XOR-4 swizzle
// ---------------------------------------------------------------------------
__global__ __launch_bounds__(256) void pack_k(
    const float* __restrict__ w, unsigned short* __restrict__ out, int taps)
{
    const int e = blockIdx.x * 256 + threadIdx.x;
    const int kslot = e & 31;
    const int ocl   = (e >> 5) & 127;
    const int icc   = (e >> 12) & 7;
    const int oct   = (e >> 15) & 1;
    const int off   = e >> 16;
    const int oc = oct * 128 + ocl;
    const int q  = kslot >> 3, j = kslot & 7;
    const int ic = icc * 32 + ((q ^ ((ocl >> 2) & 3)) << 3) + j;
    out[e] = f2bf(w[((size_t)oc * C + ic) * taps + off]);
}

// ---------------------------------------------------------------------------
// pack the four 1x1 weight matrices in ONE launch.  grid = 1024
// ---------------------------------------------------------------------------
__global__ __launch_bounds__(256) void pack4_k(
    const float* __restrict__ wq, const float* __restrict__ wk,
    const float* __restrict__ wv, const float* __restrict__ wp,
    unsigned short* __restrict__ oq, unsigned short* __restrict__ ok,
    unsigned short* __restrict__ ov, unsigned short* __restrict__ op)
{
    const int bid  = blockIdx.x;
    const int wsel = bid >> 8;
    const int e    = (bid & 255) * 256 + threadIdx.x;
    const float* w = (wsel == 0) ? wq : (wsel == 1) ? wk : (wsel == 2) ? wv : wp;
    unsigned short* out = (wsel == 0) ? oq : (wsel == 1) ? ok : (wsel == 2) ? ov : op;
    const int kslot = e & 31;
    const int ocl   = (e >> 5) & 127;
    const int icc   = (e >> 12) & 7;
    const int oct   = (e >> 15) & 1;
    const int oc = oct * 128 + ocl;
    const int q  = kslot >> 3, j = kslot & 7;
    const int ic = icc * 32 + ((q ^ ((ocl >> 2) & 3)) << 3) + j;
    out[e] = f2bf(w[(size_t)oc * C + ic]);
}

// ---------------------------------------------------------------------------
// Fused dual 3x3 conv (IEM + NEM), BK=64, r3 single-buffer barrier structure.
// BN sum/sumsq fused contention-free (LDS reduce + per-block slot store).
// Block: 256 thr = 4 waves (2x2), tile 128oc x 128px. grid = 2048 (swizzled).
// launch_bounds(256,3): LDS 50KB x3 = 150 <= 160KB, 96 VGPR x 3w/SIMD = 288
// <= 512 -> 3 blocks/CU (was 2).  Third resident block hides barrier drain.
// ---------------------------------------------------------------------------
__global__ __launch_bounds__(256, 3) void conv2_k(
    const unsigned short* __restrict__ xT,
    const unsigned short* __restrict__ Wp0, const unsigned short* __restrict__ Wp1,
    unsigned short* __restrict__ out0, unsigned short* __restrict__ out1,
    const unsigned short* __restrict__ zbuf, float* __restrict__ stats_part)
{
    __shared__ unsigned short As[2][2][128 * 32];   // [set][kc]  32KB
    __shared__ unsigned short Bs[2][128 * 32];      // [kc]       16KB
    __shared__ float sstat[2][128][2];              // [set][loc][sum|ssq] 2KB

    const int id  = swz2048(blockIdx.x);
    const int oct = id & 1;
    const int ch  = (id >> 1) & 1;
    const int r   = (id >> 2) & 255;
    const int b   = id >> 10;
    const int px0 = ch * 128;

    const int t  = threadIdx.x;
    const int wv = t >> 6;
    const int l  = t & 63;
    const int wm = (wv >> 1) * 64;
    const int wn = (wv & 1) * 64;

    // zero stats LDS (first K-loop barrier orders this before epilogue use)
    ((float*)sstat)[t]       = 0.f;
    ((float*)sstat)[t + 256] = 0.f;

    // swizzled quad for frag reads
    const int qp = (l >> 4) ^ ((l >> 2) & 3);
    int a_off[4], b_off[4];
#pragma unroll
    for (int i = 0; i < 4; i++) {
        a_off[i] = (wm + i * 16 + (l & 15)) * 64 + qp * 16;   // bytes
        b_off[i] = (wn + i * 16 + (l & 15)) * 64 + qp * 16;
    }
    // B staging: lane l stages LDS slot row px=(wv*32+i*16+(l>>2)), quad (l&3)
    const int spx_base = wv * 32 + (l >> 2);
    const int skk0 = (((l & 3) ^ (l >> 4)) << 3);            // source k-group (elems)

    // valid taps are a contiguous range (block-uniform)
    const int off_lo = (r == 0) ? 3 : 0;
    const int off_hi = (r == 255) ? 6 : 9;

    f32x4 acc[2][4][4];
#pragma unroll
    for (int s = 0; s < 2; s++)
#pragma unroll
        for (int i = 0; i < 4; i++)
#pragma unroll
            for (int j = 0; j < 4; j++) acc[s][i][j] = (f32x4){0.f, 0.f, 0.f, 0.f};

#pragma unroll 1
    for (int off = off_lo; off < off_hi; ++off) {
        const int dy = off / 3, dx = off - dy * 3;
        const int rr = r + dy - 1;            // in [0,255] by construction
        const size_t rowpix = (size_t)(b * HW) + (size_t)rr * W;
#pragma unroll 1
        for (int ip = 0; ip < 4; ++ip) {      // icc pair: icc = 2*ip, 2*ip+1
            __syncthreads();   // previous pair's frag reads done
            // ---- stage A both sets, both kc (icc pair = 16KB contiguous) ----
            const size_t wofs = ((size_t)(((off * 2 + oct) * 8 + ip * 2)) * 4096) * 2
                                + wv * 2048 + l * 16;
#pragma unroll
            for (int kc = 0; kc < 2; kc++) {
                char* A0 = (char*)As[0][kc] + wv * 2048;
                char* A1 = (char*)As[1][kc] + wv * 2048;
                const size_t o = wofs + (size_t)kc * 8192;
                gld_lds16((const char*)Wp0 + o, A0);
                gld_lds16((const char*)Wp0 + o + 1024, A0 + 1024);
                gld_lds16((const char*)Wp1 + o, A1);
                gld_lds16((const char*)Wp1 + o + 1024, A1 + 1024);
                // ---- stage B (shared by both sets) ----
                const int ic0 = (ip * 2 + kc) * 32;
                char* BsB = (char*)Bs[kc] + wv * 2048;
#pragma unroll
                for (int i = 0; i < 2; i++) {
                    const int px = spx_base + i * 16;
                    const int cx = px0 + px + dx - 1;
                    const void* g = ((unsigned)cx > 255u)
                        ? (const void*)zbuf
                        : (const void*)(xT + ((rowpix + cx) * C + ic0 + skk0));
                    gld_lds16(g, BsB + i * 1024);
                }
            }
            asm volatile("s_waitcnt vmcnt(0)" ::: "memory");
            __syncthreads();
            // ---- fragments + 64 MFMAs (2 kc x 2 sets x 16) ----
#pragma unroll
            for (int kc = 0; kc < 2; kc++) {
                bf16x8 af0[4], af1[4], bfr[4];
#pragma unroll
                for (int i = 0; i < 4; i++) {
                    af0[i] = *(const bf16x8*)((const char*)As[0][kc] + a_off[i]);
                    af1[i] = *(const bf16x8*)((const char*)As[1][kc] + a_off[i]);
                }
#pragma unroll
                for (int i = 0; i < 4; i++)
                    bfr[i] = *(const bf16x8*)((const char*)Bs[kc] + b_off[i]);
#pragma unroll
                for (int mi = 0; mi < 4; mi++)
#pragma unroll
                    for (int nj = 0; nj < 4; nj++) {
                        acc[0][mi][nj] = __builtin_amdgcn_mfma_f32_16x16x32_bf16(
                            af0[mi], bfr[nj], acc[0][mi][nj], 0, 0, 0);
                        acc[1][mi][nj] = __builtin_amdgcn_mfma_f32_16x16x32_bf16(
                            af1[mi], bfr[nj], acc[1][mi][nj], 0, 0, 0);
                    }
            }
        }
    }

    // ---- epilogue: NCHW bf16 stores + LDS-reduced BN partials ----
    const int colpx = px0 + wn + (l & 15);
    const int rowoc = oct * 128 + wm + (l >> 4) * 4;
#pragma unroll
    for (int s = 0; s < 2; s++) {
        unsigned short* ob = s ? out1 : out0;
#pragma unroll
        for (int mi = 0; mi < 4; mi++) {
#pragma unroll
            for (int rg = 0; rg < 4; rg++) {
                const int oc = rowoc + mi * 16 + rg;
                float ps = 0.f, pq = 0.f;
#pragma unroll
                for (int nj = 0; nj < 4; nj++) {
                    const float v = acc[s][mi][nj][rg];
                    ps += v;
                    pq = fmaf(v, v, pq);
                    const int px = colpx + nj * 16;
                    const size_t idx = ((size_t)(b * C + oc)) * HW + (size_t)r * W + px;
                    ob[idx] = f2bf(v);
                }
                // reduce over the 16 px-lanes (same oc for all l&15)
                ps += __shfl_xor(ps, 1);  pq += __shfl_xor(pq, 1);
                ps += __shfl_xor(ps, 2);  pq += __shfl_xor(pq, 2);
                ps += __shfl_xor(ps, 4);  pq += __shfl_xor(pq, 4);
                ps += __shfl_xor(ps, 8);  pq += __shfl_xor(pq, 8);
                if ((l & 15) == 0) {
                    const int loc = wm + (l >> 4) * 4 + mi * 16 + rg;  // 0..127
                    atomicAdd(&sstat[s][loc][0], ps);
                    atomicAdd(&sstat[s][loc][1], pq);
                }
            }
        }
    }
    __syncthreads();
    // one coalesced 2KB store: entry t = s*128 + loc
    stats_part[(size_t)id * 512 + t * 2 + 0] = ((float(*)[2])sstat)[t][0];
    stats_part[(size_t)id * 512 + t * 2 + 1] = ((float(*)[2])sstat)[t][1];
}

// ---------------------------------------------------------------------------
// BN reduce + finalize: sum stats_part over the 1024 matching block slots
// per (set, oc), then emit fused scale/shift.  grid = 512 (s*256 + oc).
// ---------------------------------------------------------------------------
__global__ __launch_bounds__(256) void bn_reduce_k(
    const float* __restrict__ stats_part,
    const float* __restrict__ g0, const float* __restrict__ b0,
    const float* __restrict__ g1, const float* __restrict__ b1,
    float* __restrict__ scl0, float* __restrict__ shf0,
    float* __restrict__ scl1, float* __restrict__ shf1)
{
    const int s   = blockIdx.x >> 8;
    const int gc  = blockIdx.x & 255;
    const int oct = gc >> 7;
    const int loc = gc & 127;
    const int t   = threadIdx.x;
    const int ent = (s * 128 + loc) * 2;

    float ps = 0.f, pq = 0.f;
#pragma unroll
    for (int m = 0; m < 4; m++) {
        const int id = oct + 2 * (t + 256 * m);   // ids with id&1 == oct
        ps += stats_part[(size_t)id * 512 + ent];
        pq += stats_part[(size_t)id * 512 + ent + 1];
    }
    __shared__ float rs[256], rq[256];
    rs[t] = ps; rq[t] = pq;
    __syncthreads();
    for (int o = 128; o > 0; o >>= 1) {
        if (t < o) { rs[t] += rs[t + o]; rq[t] += rq[t + o]; }
        __syncthreads();
    }
    if (t == 0) {
        const float n    = (float)Bn * HW;
        const float mean = rs[0] / n;
        const float var  = rq[0] / n - mean * mean;
        const float g    = s ? g1[gc] : g0[gc];
        const float be   = s ? b1[gc] : b0[gc];
        const float sc   = g * rsqrtf(var + 1e-5f);
        if (s) { scl1[gc] = sc; shf1[gc] = be - mean * sc; }
        else   { scl0[gc] = sc; shf0[gc] = be - mean * sc; }
    }
}

// ---------------------------------------------------------------------------
// Fused dual 1x1 GEMM (Q + K).  BK=64, single-buffer.
// Block: 256 thr = 4 waves (2x2), tile 128oc x 128px. grid = 2048 (swizzled).
// LDS 64KB -> 2 blocks/CU max.
// ---------------------------------------------------------------------------
__global__ __launch_bounds__(256, 2) void gemm2_k(
    const unsigned short* __restrict__ qin, const unsigned short* __restrict__ kin,
    const unsigned short* __restrict__ Wpq, const unsigned short* __restrict__ Wpk,
    unsigned short* __restrict__ outq, unsigned short* __restrict__ outk)
{
    __shared__ unsigned short As[2][2][128 * 32];   // [set][kc] 32KB
    __shared__ unsigned short Bs[2][2][128 * 32];   // [set][kc] 32KB

    const int id  = swz2048(blockIdx.x);
    const int oct = id & 1;
    const int ch  = (id >> 1) & 1;
    const int r   = (id >> 2) & 255;
    const int b   = id >> 10;
    const int px0 = ch * 128;

    const int t  = threadIdx.x;
    const int wv = t >> 6;
    const int l  = t & 63;
    const int wm = (wv >> 1) * 64;
    const int wn = (wv & 1) * 64;

    const int qp = (l >> 4) ^ ((l >> 2) & 3);
    int a_off[4], b_off[4];
#pragma unroll
    for (int i = 0; i < 4; i++) {
        a_off[i] = (wm + i * 16 + (l & 15)) * 64 + qp * 16;
        b_off[i] = (wn + i * 16 + (l & 15)) * 64 + qp * 16;
    }
    const int spx_base = wv * 32 + (l >> 2);
    const int skk0 = (((l & 3) ^ (l >> 4)) << 3);

    const size_t rowpix = (size_t)(b * HW) + (size_t)r * W;

    f32x4 acc[2][4][4];
#pragma unroll
    for (int s = 0; s < 2; s++)
#pragma unroll
        for (int i = 0; i < 4; i++)
#pragma unroll
            for (int j = 0; j < 4; j++) acc[s][i][j] = (f32x4){0.f, 0.f, 0.f, 0.f};

#pragma unroll 1
    for (int ip = 0; ip < 4; ++ip) {
        __syncthreads();
#pragma unroll
        for (int kc = 0; kc < 2; kc++) {
            const int icc = ip * 2 + kc;
            const size_t wofs = ((size_t)(oct * 8 + icc) * 4096) * 2 + wv * 2048 + l * 16;
            char* Aq = (char*)As[0][kc] + wv * 2048;
            char* Ak = (char*)As[1][kc] + wv * 2048;
            gld_lds16((const char*)Wpq + wofs, Aq);
            gld_lds16((const char*)Wpq + wofs + 1024, Aq + 1024);
            gld_lds16((const char*)Wpk + wofs, Ak);
            gld_lds16((const char*)Wpk + wofs + 1024, Ak + 1024);
            const int ic0 = icc * 32;
            char* Bq = (char*)Bs[0][kc] + wv * 2048;
            char* Bk = (char*)Bs[1][kc] + wv * 2048;
#pragma unroll
            for (int i = 0; i < 2; i++) {
                const int cx = px0 + spx_base + i * 16;
                gld_lds16((const void*)(qin + ((rowpix + cx) * C + ic0 + skk0)), Bq + i * 1024);
                gld_lds16((const void*)(kin + ((rowpix + cx) * C + ic0 + skk0)), Bk + i * 1024);
            }
        }
        asm volatile("s_waitcnt vmcnt(0)" ::: "memory");
        __syncthreads();
#pragma unroll
        for (int kc = 0; kc < 2; kc++) {
#pragma unroll
            for (int s = 0; s < 2; s++) {
                bf16x8 af[4], bfr[4];
#pragma unroll
                for (int i = 0; i < 4; i++) {
                    af[i]  = *(const bf16x8*)((const char*)As[s][kc] + a_off[i]);
                    bfr[i] = *(const bf16x8*)((const char*)Bs[s][kc] + b_off[i]);
                }
#pragma unroll
                for (int mi = 0; mi < 4; mi++)
#pragma unroll
                    for (int nj = 0; nj < 4; nj++)
                        acc[s][mi][nj] = __builtin_amdgcn_mfma_f32_16x16x32_bf16(
                            af[mi], bfr[nj], acc[s][mi][nj], 0, 0, 0);
            }
        }
    }

    // ---- epilogue: NHWC bf16 for both outputs ----
    const int colpx = px0 + wn + (l & 15);
    const int rowoc = oct * 128 + wm + (l >> 4) * 4;
    const size_t pxg = (size_t)(b * HW) + (size_t)r * W;
#pragma unroll
    for (int s = 0; s < 2; s++) {
        unsigned short* ob = s ? outk : outq;
#pragma unroll
        for (int mi = 0; mi < 4; mi++) {
#pragma unroll
            for (int nj = 0; nj < 4; nj++) {
                __attribute__((aligned(8))) unsigned short rv[4];
#pragma unroll
                for (int rg = 0; rg < 4; rg++) rv[rg] = f2bf(acc[s][mi][nj][rg]);
                const int oc = rowoc + mi * 16;
                const int px = colpx + nj * 16;
                *(uint2*)(ob + (pxg + px) * C + oc) = *(const uint2*)rv;
            }
        }
    }
}

// ---------------------------------------------------------------------------
// MFMA GEMM (1x1 conv, K = 256), BK=64 single-buffer (4 barrier-pairs).
// B input: NHWC bf16.  Output: NCHW fp32 / NHWC bf16.
// Block: 256 thr = 4 waves (2x2), tile 128oc x 128px. grid = 2048 (swizzled).
// launch_bounds(256,4): LDS 32KB x4 = 128 <= 160KB -> 4 blocks/CU (was 2).
// ---------------------------------------------------------------------------
template<bool F32OUT, bool NHWC_OUT>
__global__ __launch_bounds__(256, 4) void gemm_k(
    const unsigned short* __restrict__ xT, const unsigned short* __restrict__ Wp,
    unsigned short* __restrict__ outb, float* __restrict__ outf)
{
    __shared__ unsigned short As[2][128 * 32];   // [kc] 16KB
    __shared__ unsigned short Bs[2][128 * 32];   // [kc] 16KB

    const int id  = swz2048(blockIdx.x);
    const int oct = id & 1;
    const int ch  = (id >> 1) & 1;
    const int r   = (id >> 2) & 255;
    const int b   = id >> 10;
    const int px0 = ch * 128;

    const int t  = threadIdx.x;
    const int wv = t >> 6;
    const int l  = t & 63;
    const int wm = (wv >> 1) * 64;
    const int wn = (wv & 1) * 64;

    const int qp = (l >> 4) ^ ((l >> 2) & 3);
    int a_off[4], b_off[4];
#pragma unroll
    for (int i = 0; i < 4; i++) {
        a_off[i] = (wm + i * 16 + (l & 15)) * 64 + qp * 16;
        b_off[i] = (wn + i * 16 + (l & 15)) * 64 + qp * 16;
    }
    const int spx_base = wv * 32 + (l >> 2);
    const int skk0 = (((l & 3) ^ (l >> 4)) << 3);

    const size_t rowpix = (size_t)(b * HW) + (size_t)r * W;

    f32x4 acc[4][4];
#pragma unroll
    for (int i = 0; i < 4; i++)
#pragma unroll
        for (int j = 0; j < 4; j++) acc[i][j] = (f32x4){0.f, 0.f, 0.f, 0.f};

#pragma unroll 1
    for (int ip = 0; ip < 4; ++ip) {
        __syncthreads();
#pragma unroll
        for (int kc = 0; kc < 2; kc++) {
            const int icc = ip * 2 + kc;
            const char* Ag = (const char*)Wp +
                ((size_t)(oct * 8 + icc) * 4096) * 2 + wv * 2048 + l * 16;
            char* AsB = (char*)As[kc] + wv * 2048;
            gld_lds16(Ag, AsB);
            gld_lds16(Ag + 1024, AsB + 1024);
            const int ic0 = icc * 32;
            char* BsB = (char*)Bs[kc] + wv * 2048;
#pragma unroll
            for (int i = 0; i < 2; i++) {
                const int cx = px0 + spx_base + i * 16;
                gld_lds16((const void*)(xT + ((rowpix + cx) * C + ic0 + skk0)), BsB + i * 1024);
            }
        }
        asm volatile("s_waitcnt vmcnt(0)" ::: "memory");
        __syncthreads();
#pragma unroll
        for (int kc = 0; kc < 2; kc++) {
            bf16x8 af[4], bfr[4];
#pragma unroll
            for (int i = 0; i < 4; i++) {
                af[i]  = *(const bf16x8*)((const char*)As[kc] + a_off[i]);
                bfr[i] = *(const bf16x8*)((const char*)Bs[kc] + b_off[i]);
            }
#pragma unroll
            for (int mi = 0; mi < 4; mi++)
#pragma unroll
                for (int nj = 0; nj < 4; nj++)
                    acc[mi][nj] = __builtin_amdgcn_mfma_f32_16x16x32_bf16(
                        af[mi], bfr[nj], acc[mi][nj], 0, 0, 0);
        }
    }

    // ---- epilogue: C/D layout col=lane&15, row=(lane>>4)*4+reg ----
    const int colpx = px0 + wn + (l & 15);
    const int rowoc = oct * 128 + wm + (l >> 4) * 4;
    if (NHWC_OUT) {
        const size_t pxg = (size_t)(b * HW) + (size_t)r * W;
#pragma unroll
        for (int mi = 0; mi < 4; mi++) {
#pragma unroll
            for (int nj = 0; nj < 4; nj++) {
                __attribute__((aligned(8))) unsigned short rv[4];
#pragma unroll
                for (int rg = 0; rg < 4; rg++) rv[rg] = f2bf(acc[mi][nj][rg]);
                const int oc = rowoc + mi * 16;
                const int px = colpx + nj * 16;
                *(uint2*)(outb + (pxg + px) * C + oc) = *(const uint2*)rv;
            }
        }
    } else {
#pragma unroll
        for (int mi = 0; mi < 4; mi++) {
#pragma unroll
            for (int nj = 0; nj < 4; nj++) {
#pragma unroll
                for (int rg = 0; rg < 4; rg++) {
                    const int oc = rowoc + mi * 16 + rg;
                    const int px = colpx + nj * 16;
                    const size_t idx = ((size_t)(b * C + oc)) * HW + (size_t)r * W + px;
                    if (F32OUT) outf[idx] = acc[mi][nj][rg];
                    else        outb[idx] = f2bf(acc[mi][nj][rg]);
                }
            }
        }
    }
}

// ---------------------------------------------------------------------------
// depthwise 3x3 with BN+relu6 fused on input read + fused per-pixel channel
// mean partials.  MERGED IEM+NEM, 32-channel blocks (27KB LDS, 5-6 blk/CU).
// In: NCHW bf16 conv raw (per set).  Out: NHWC bf16 + smean fp32 [B*HW].
// grid = 32768: c0=(id&7)*32, w0=((id>>3)&3)*64, r=(id>>5)&255,
//               b=(id>>13)&1, set=id>>14
// ---------------------------------------------------------------------------
__global__ __launch_bounds__(256) void dwconv_k(
    const unsigned short* __restrict__ a0, const unsigned short* __restrict__ a1,
    const float* __restrict__ scl0, const float* __restrict__ shf0,
    const float* __restrict__ scl1, const float* __restrict__ shf1,
    const float* __restrict__ wd0, const float* __restrict__ wd1,
    unsigned short* __restrict__ out0, unsigned short* __restrict__ out1,
    float* __restrict__ sm0, float* __restrict__ sm1)
{
    __shared__ float tile[32][3][67];   // cols w0-1 .. w0+65 -> idx 0..65
    __shared__ float wds[32 * 9];
    __shared__ float sscl[32], sshf[32];

    const int id  = blockIdx.x;
    const int c0  = (id & 7) * 32;
    const int w0  = ((id >> 3) & 3) * 64;
    const int r   = (id >> 5) & 255;
    const int b   = (id >> 13) & 1;
    const int set = id >> 14;
    const int t   = threadIdx.x;

    const unsigned short* a   = set ? a1 : a0;
    const float* scale        = set ? scl1 : scl0;
    const float* shift        = set ? shf1 : shf0;
    const float* wd           = set ? wd1 : wd0;
    unsigned short* out       = set ? out1 : out0;
    float* smean              = set ? sm1 : sm0;

    for (int i = t; i < 288; i += 256) wds[i] = wd[c0 * 9 + i];
    if (t < 32) { sscl[t] = scale[c0 + t]; sshf[t] = shift[c0 + t]; }
    __syncthreads();

    // main staging: 32c x 3row x 16seg of 4 elems (1536 items, 6 per thread)
    for (int i = t; i < 1536; i += 256) {
        const int c   = i / 48;
        const int rem = i - c * 48;
        const int row = rem >> 4, seg = rem & 15;
        const int rr  = r + row - 1;
        float f0 = 0.f, f1 = 0.f, f2 = 0.f, f3 = 0.f;
        if ((unsigned)rr < 256u) {
            const uint2 v = *(const uint2*)(a + ((size_t)(b * C + c0 + c)) * HW
                                              + (size_t)rr * W + w0 + seg * 4);
            const float sc = sscl[c], sh = sshf[c];
            f0 = fminf(fmaxf(fmaf(bflo(v.x), sc, sh), 0.f), 6.f);
            f1 = fminf(fmaxf(fmaf(bfhi(v.x), sc, sh), 0.f), 6.f);
            f2 = fminf(fmaxf(fmaf(bflo(v.y), sc, sh), 0.f), 6.f);
            f3 = fminf(fmaxf(fmaf(bfhi(v.y), sc, sh), 0.f), 6.f);
        }
        float* dst = &tile[c][row][1 + seg * 4];
        dst[0] = f0; dst[1] = f1; dst[2] = f2; dst[3] = f3;
    }
    // edges: 32c x 3row x 2side (192 items)
    for (int i = t; i < 192; i += 256) {
        const int c   = i / 6;
        const int rem = i - c * 6;
        const int row = rem >> 1, side = rem & 1;
        const int rr  = r + row - 1;
        const int col = side ? (w0 + 64) : (w0 - 1);
        float v = 0.f;
        if ((unsigned)rr < 256u && (unsigned)col < 256u) {
            float u = bf2f(a[((size_t)(b * C + c0 + c)) * HW + (size_t)rr * W + col]);
            v = fminf(fmaxf(fmaf(u, sscl[c], sshf[c]), 0.f), 6.f);
        }
        tile[c][row][side ? 65 : 0] = v;
    }
    __syncthreads();

    const int px = t >> 2, csub = t & 3;
    __attribute__((aligned(16))) unsigned short res[8];
    float psum = 0.f;
#pragma unroll
    for (int k = 0; k < 8; k++) {
        const int c = csub * 8 + k;
        const float* wp = &wds[c * 9];
        float accv = 0.f;
#pragma unroll
        for (int dy = 0; dy < 3; dy++)
#pragma unroll
            for (int dx = 0; dx < 3; dx++)
                accv = fmaf(tile[c][dy][px + dx], wp[dy * 3 + dx], accv);
        res[k] = f2bf(accv);
        psum += accv;
    }
    unsigned short* o = out + ((size_t)(b * HW) + (size_t)r * W + w0 + px) * C + c0 + csub * 8;
    *(uint4*)o = *(const uint4*)&res[0];

    // fused channel-mean partial: quad-reduce (lanes t, t^1, t^2 share px)
    psum += __shfl_xor(psum, 1);
    psum += __shfl_xor(psum, 2);
    if (csub == 0)
        atomicAdd(&smean[(size_t)(b * HW) + (size_t)r * W + w0 + px], psum * (1.f / C));
}

// ---------------------------------------------------------------------------
// windowed attention via MFMA. One wave per (b, head, wy, wx) window.
// q,k,v: NHWC bf16.  out: NHWC bf16.  setprio(1) around MFMA clusters (T5).
// ---------------------------------------------------------------------------
__global__ __launch_bounds__(64) void attn_k(
    const unsigned short* __restrict__ q, const unsigned short* __restrict__ k,
    const unsigned short* __restrict__ v, const float* __restrict__ si,
    const float* __restrict__ sn, const float* __restrict__ temp,
    unsigned short* __restrict__ out)
{
    __shared__ unsigned short Pl[64][72];   // P rows: pitch 144B (16B aligned)
    __shared__ unsigned short Vt[32][72];   // V^T rows: [d][kpix]

    const int id   = blockIdx.x;
    const int wx   = id & 31;
    const int wy   = (id >> 5) & 31;
    const int head = (id >> 10) & 7;
    const int b    = id >> 13;
    const int l    = threadIdx.x;
    const int pl15 = l & 15;
    const int g    = l >> 4;
    const int ch0  = head * 32;
    const int base = wy * 8 * W + wx * 8;       // window origin pixel
    const size_t bb = (size_t)b * HW;

    // ---- load Q/K fragments (A-frag layout: row=lane&15, kgrp=lane>>4) ----
    uint4 qv[4], kv[4];
    float qss[4], kss[4];
#pragma unroll
    for (int i = 0; i < 4; i++) {
        const int p = i * 16 + pl15;
        const size_t a = (bb + base + (p >> 3) * W + (p & 7)) * C + ch0 + g * 8;
        qv[i] = *(const uint4*)(q + a);
        kv[i] = *(const uint4*)(k + a);
        // partial squared norms over this lane's 8 channels
        float s0 = 0.f, s1 = 0.f;
        {
            uint4 u = qv[i];
            float f;
            f = bflo(u.x); s0 = fmaf(f, f, s0);  f = bfhi(u.x); s0 = fmaf(f, f, s0);
            f = bflo(u.y); s0 = fmaf(f, f, s0);  f = bfhi(u.y); s0 = fmaf(f, f, s0);
            f = bflo(u.z); s0 = fmaf(f, f, s0);  f = bfhi(u.z); s0 = fmaf(f, f, s0);
            f = bflo(u.w); s0 = fmaf(f, f, s0);  f = bfhi(u.w); s0 = fmaf(f, f, s0);
        }
        {
            uint4 u = kv[i];
            float f;
            f = bflo(u.x); s1 = fmaf(f, f, s1);  f = bfhi(u.x); s1 = fmaf(f, f, s1);
            f = bflo(u.y); s1 = fmaf(f, f, s1);  f = bfhi(u.y); s1 = fmaf(f, f, s1);
            f = bflo(u.z); s1 = fmaf(f, f, s1);  f = bfhi(u.z); s1 = fmaf(f, f, s1);
            f = bflo(u.w); s1 = fmaf(f, f, s1);  f = bfhi(u.w); s1 = fmaf(f, f, s1);
        }
        // full 32-ch norms: combine the 4 d-groups (lanes l, l^16, l^32, l^48)
        s0 += __shfl_xor(s0, 16); s0 += __shfl_xor(s0, 32);
        s1 += __shfl_xor(s1, 16); s1 += __shfl_xor(s1, 32);
        qss[i] = s0; kss[i] = s1;
    }

    // ---- stage V^T into LDS: lane l owns window pixel l (32 scalar writes) ----
    {
        const size_t a = (bb + base + (l >> 3) * W + (l & 7)) * C + ch0;
        const uint4* vp = (const uint4*)(v + a);
#pragma unroll
        for (int i = 0; i < 4; i++) {
            uint4 vv = vp[i];
            Vt[i * 8 + 0][l] = (unsigned short)(vv.x);
            Vt[i * 8 + 1][l] = (unsigned short)(vv.x >> 16);
            Vt[i * 8 + 2][l] = (unsigned short)(vv.y);
            Vt[i * 8 + 3][l] = (unsigned short)(vv.y >> 16);
            Vt[i * 8 + 4][l] = (unsigned short)(vv.z);
            Vt[i * 8 + 5][l] = (unsigned short)(vv.z >> 16);
            Vt[i * 8 + 6][l] = (unsigned short)(vv.w);
            Vt[i * 8 + 7][l] = (unsigned short)(vv.w >> 16);
        }
    }

    // ---- per-pixel scales ----
    const float tsc = temp[head] * 0.17677669529663689f;   // 32^-0.5
    float qmul[4], kscl[4];
#pragma unroll
    for (int i = 0; i < 4; i++) {
        const int p = i * 16 + pl15;
        const size_t pg = bb + base + (p >> 3) * W + (p & 7);
        const float il = si[pg];
        const float nz = sn[pg];
        qmul[i] = (1.f + il) * tsc / fmaxf(sqrtf(qss[i]), 1e-12f);
        kscl[i] = fminf(fmaxf(1.f - nz, 0.f), 1.f) / fmaxf(sqrtf(kss[i]), 1e-12f);
    }

    // ---- S = Q * K^T: 16 MFMAs ----
    f32x4 acc[4][4];
    __builtin_amdgcn_s_setprio(1);
#pragma unroll
    for (int qi = 0; qi < 4; qi++)
#pragma unroll
        for (int kj = 0; kj < 4; kj++)
            acc[qi][kj] = __builtin_amdgcn_mfma_f32_16x16x32_bf16(
                u2b(qv[qi]), u2b(kv[kj]), (f32x4){0.f, 0.f, 0.f, 0.f}, 0, 0, 0);
    __builtin_amdgcn_s_setprio(0);

    // ---- scale + softmax (rows owned: q = qi*16 + g*4 + rg) + P -> LDS ----
    float inv[4][4];
#pragma unroll
    for (int qi = 0; qi < 4; qi++) {
#pragma unroll
        for (int rg = 0; rg < 4; rg++) {
            const float qm = __shfl(qmul[qi], (g << 2) + rg);
            float s[4];
#pragma unroll
            for (int kj = 0; kj < 4; kj++) s[kj] = acc[qi][kj][rg] * kscl[kj] * qm;
            float mx = fmaxf(fmaxf(s[0], s[1]), fmaxf(s[2], s[3]));
            mx = fmaxf(mx, __shfl_xor(mx, 1));
            mx = fmaxf(mx, __shfl_xor(mx, 2));
            mx = fmaxf(mx, __shfl_xor(mx, 4));
            mx = fmaxf(mx, __shfl_xor(mx, 8));
            float sum = 0.f;
#pragma unroll
            for (int kj = 0; kj < 4; kj++) {
                const float e = __expf(s[kj] - mx);
                acc[qi][kj][rg] = e;
                sum += e;
            }
            sum += __shfl_xor(sum, 1);
            sum += __shfl_xor(sum, 2);
            sum += __shfl_xor(sum, 4);
            sum += __shfl_xor(sum, 8);
            inv[qi][rg] = 1.f / sum;
            const int qrow = qi * 16 + (g << 2) + rg;
#pragma unroll
            for (int kj = 0; kj < 4; kj++)
                Pl[qrow][pl15 + 16 * kj] = f2bf(acc[qi][kj][rg]);
        }
    }

    // ---- O = P * V: 16 MFMAs (K-dim = 64 k-pixels, 2 chunks of 32) ----
    f32x4 oacc[4][2];
#pragma unroll
    for (int qi = 0; qi < 4; qi++)
#pragma unroll
        for (int dj = 0; dj < 2; dj++) oacc[qi][dj] = (f32x4){0.f, 0.f, 0.f, 0.f};

#pragma unroll
    for (int kc = 0; kc < 2; kc++) {
        const bf16x8 vb0 = *(const bf16x8*)&Vt[pl15][kc * 32 + g * 8];
        const bf16x8 vb1 = *(const bf16x8*)&Vt[pl15 + 16][kc * 32 + g * 8];
        __builtin_amdgcn_s_setprio(1);
#pragma unroll
        for (int qi = 0; qi < 4; qi++) {
            const bf16x8 pa = *(const bf16x8*)&Pl[qi * 16 + pl15][kc * 32 + g * 8];
            oacc[qi][0] = __builtin_amdgcn_mfma_f32_16x16x32_bf16(pa, vb0, oacc[qi][0], 0, 0, 0);
            oacc[qi][1] = __builtin_amdgcn_mfma_f32_16x16x32_bf16(pa, vb1, oacc[qi][1], 0, 0, 0);
        }
        __builtin_amdgcn_s_setprio(0);
    }

    // ---- epilogue: row q = qi*16 + g*4 + rg, col d = pl15 + 16*dj ----
#pragma unroll
    for (int qi = 0; qi < 4; qi++) {
#pragma unroll
        for (int rg = 0; rg < 4; rg++) {
            const int qrow = qi * 16 + (g << 2) + rg;
            const size_t oaddr = (bb + base + (qrow >> 3) * W + (qrow & 7)) * C + ch0;
            const float sc = inv[qi][rg];
            out[oaddr + pl15]      = f2bf(oacc[qi][0][rg] * sc);
            out[oaddr + 16 + pl15] = f2bf(oacc[qi][1][rg] * sc);
        }
    }
}

// ---------------------------------------------------------------------------
extern "C" void kernel_launch(void* const* d_in, const int* in_sizes, int n_in,
                              void* d_out, int out_size, void* d_ws, size_t ws_size,
                              hipStream_t stream)
{
    const float* x        = (const float*)d_in[0];
    const float* w_iem    = (const float*)d_in[1];
    const float* g_iem    = (const float*)d_in[2];
    const float* b_iem    = (const float*)d_in[3];
    const float* w_nem    = (const float*)d_in[4];
    const float* g_nem    = (const float*)d_in[5];
    const float* b_nem    = (const float*)d_in[6];
    const float* w_iem_dw = (const float*)d_in[7];
    const float* w_nem_dw = (const float*)d_in[8];
    const float* w_q      = (const float*)d_in[9];
    const float* w_k      = (const float*)d_in[10];
    const float* w_v      = (const float*)d_in[11];
    const float* w_proj   = (const float*)d_in[12];
    const float* temp     = (const float*)d_in[13];

    // workspace carve-up (bytes)
    char* p = (char*)d_ws;
    unsigned short* zbuf = (unsigned short*)p;      p += 256;
    float* scl0 = (float*)p;                        p += 256 * 4;
    float* shf0 = (float*)p;                        p += 256 * 4;
    float* scl1 = (float*)p;                        p += 256 * 4;
    float* shf1 = (float*)p;                        p += 256 * 4;
    float* stats_part = (float*)p;                  p += (size_t)2048 * 512 * 4;  // 4MB
    float* sI  = (float*)p;                         p += (size_t)Bn * HW * 4;
    float* sN  = (float*)p;                         p += (size_t)Bn * HW * 4;
    unsigned short* Wp_iem = (unsigned short*)p;    p += 589824 * 2;
    unsigned short* Wp_nem = (unsigned short*)p;    p += 589824 * 2;
    unsigned short* Wpq = (unsigned short*)p;       p += 65536 * 2;
    unsigned short* Wpk = (unsigned short*)p;       p += 65536 * 2;
    unsigned short* Wpv = (unsigned short*)p;       p += 65536 * 2;
    unsigned short* Wpp = (unsigned short*)p;       p += 65536 * 2;
    unsigned short* xT   = (unsigned short*)p;      p += Bn * CHW * 2;  // NHWC bf16
    unsigned short* bufA = (unsigned short*)p;      p += Bn * CHW * 2;  // IEM raw (NCHW) / Q (NHWC)
    unsigned short* Ibf  = (unsigned short*)p;      p += Bn * CHW * 2;  // illum NHWC / attn out NHWC
    unsigned short* Nbf  = (unsigned short*)p;      p += Bn * CHW * 2;  // noise NHWC / V (NHWC)
    unsigned short* Obf  = (unsigned short*)p;      p += Bn * CHW * 2;  // NEM raw (NCHW) / K (NHWC)

    hipMemsetAsync(zbuf, 0, 256, stream);
    hipMemsetAsync(sI, 0, (size_t)Bn * HW * 4 * 2, stream);   // sI + sN contiguous

    packx_k<<<8192, 256, 0, stream>>>(x, xT);
    pack_k<<<2304, 256, 0, stream>>>(w_iem, Wp_iem, 9);
    pack_k<<<2304, 256, 0, stream>>>(w_nem, Wp_nem, 9);
    pack4_k<<<1024, 256, 0, stream>>>(w_q, w_k, w_v, w_proj, Wpq, Wpk, Wpv, Wpp);

    // fused IEM+NEM 3x3 conv + contention-free BN partials
    conv2_k<<<2048, 256, 0, stream>>>(xT, Wp_iem, Wp_nem, bufA, Obf, zbuf, stats_part);
    bn_reduce_k<<<512, 256, 0, stream>>>(stats_part, g_iem, b_iem, g_nem, b_nem,
                                         scl0, shf0, scl1, shf1);

    // merged depthwise (both sets; BN+relu6 on read, channel-mean on write)
    dwconv_k<<<32768, 256, 0, stream>>>(bufA, Obf, scl0, shf0, scl1, shf1,
                                        w_iem_dw, w_nem_dw, Ibf, Nbf, sI, sN);

    // fused Q+K projections -> NHWC bf16 (Q->bufA, K->Obf)
    gemm2_k<<<2048, 256, 0, stream>>>(Ibf, Nbf, Wpq, Wpk, bufA, Obf);
    // V projection (Nbf consumed by gemm2 above)
    gemm_k<false, true><<<2048, 256, 0, stream>>>(xT, Wpv, Nbf, nullptr);

    attn_k<<<16384, 64, 0, stream>>>(bufA, Obf, Nbf, sI, sN, temp, Ibf);

    // final projection -> fp32 d_out (NCHW)
    gemm_k<true, false><<<2048, 256, 0, stream>>>(Ibf, Wpp, nullptr, (float*)d_out);
}

// Round 11
// 1013.813 us; speedup vs baseline: 1.0559x; 1.0559x over previous
//
#include <hip/hip_runtime.h>
#include <math.h>

// ---------------------------------------------------------------------------
// Problem constants
constexpr int Bn  = 2;
constexpr int C   = 256;
constexpr int H   = 256;
constexpr int W   = 256;
constexpr int HW  = H * W;          // 65536
constexpr size_t CHW = (size_t)C * HW;

typedef __bf16 bf16x8 __attribute__((ext_vector_type(8)));
typedef float  f32x4  __attribute__((ext_vector_type(4)));

// fp32 -> bf16 round-to-nearest-even
__device__ __forceinline__ unsigned short f2bf(float f) {
    unsigned int u = __float_as_uint(f);
    u += 0x7fffu + ((u >> 16) & 1u);
    return (unsigned short)(u >> 16);
}
__device__ __forceinline__ float bf2f(unsigned short h) {
    return __uint_as_float(((unsigned int)h) << 16);
}
// two bf16 packed in a uint -> floats (hi needs only a mask)
__device__ __forceinline__ float bflo(unsigned int u) { return __uint_as_float(u << 16); }
__device__ __forceinline__ float bfhi(unsigned int u) { return __uint_as_float(u & 0xffff0000u); }

__device__ __forceinline__ bf16x8 u2b(uint4 u) {
    union { uint4 a; bf16x8 b; } c; c.a = u; return c.b;
}

// async global->LDS, 16B per lane; LDS dest = uniform base + lane*16
__device__ __forceinline__ void gld_lds16(const void* g, void* lds) {
    __builtin_amdgcn_global_load_lds(
        (const __attribute__((address_space(1))) unsigned int*)g,
        (__attribute__((address_space(3))) unsigned int*)lds, 16, 0, 0);
}

// XCD-aware bijective swizzle for 2048-block grids (2048 % 8 == 0)
__device__ __forceinline__ int swz2048(int bid) {
    return ((bid & 7) << 8) | (bid >> 3);
}

// ---------------------------------------------------------------------------
// packx: x fp32 NCHW -> bf16 NHWC.  Tile 64c x 64px via LDS transpose.
// grid = (2*65536/64) * 4 = 8192 blocks
// ---------------------------------------------------------------------------
__global__ __launch_bounds__(256) void packx_k(
    const float* __restrict__ x, unsigned short* __restrict__ xT)
{
    __shared__ float tl[64][65];
    const int id = blockIdx.x;
    const int ct = id & 3;
    const size_t px0 = (size_t)(id >> 2) * 64;   // global pixel (incl batch)
    const int b  = (int)(px0 >> 16);
    const int hw = (int)(px0 & 65535);
    const int c0 = ct * 64;
    const int t  = threadIdx.x;

    {   // load: thread (cl, pseg): 16 px of channel cl
        const int cl = t >> 2, pseg = t & 3;
        const float* src = x + ((size_t)(b * C + c0 + cl)) * HW + hw + pseg * 16;
#pragma unroll
        for (int i = 0; i < 4; i++) {
            float4 v = *(const float4*)(src + i * 4);
            tl[cl][pseg * 16 + i * 4 + 0] = v.x;
            tl[cl][pseg * 16 + i * 4 + 1] = v.y;
            tl[cl][pseg * 16 + i * 4 + 2] = v.z;
            tl[cl][pseg * 16 + i * 4 + 3] = v.w;
        }
    }
    __syncthreads();
    {   // store: thread (pl, csec): 16 channels of pixel pl, contiguous in NHWC
        const int pl = t >> 2, csec = t & 3;
        __attribute__((aligned(16))) unsigned short rv[16];
#pragma unroll
        for (int j = 0; j < 16; j++) rv[j] = f2bf(tl[csec * 16 + j][pl]);
        unsigned short* dst = xT + (px0 + pl) * C + c0 + csec * 16;
        *(uint4*)dst       = *(const uint4*)&rv[0];
        *(uint4*)(dst + 8) = *(const uint4*)&rv[8];
    }
}

// ---------------------------------------------------------------------------
// pack weights into the LDS image the GEMM stages:
// layout [taps][oct(2)][icc(8)][ocl(128)][kslot(32)], with XOR-4 swizzle
// ---------------------------------------------------------------------------
__global__ __launch_bounds__(256) void pack_k(
    const float* __restrict__ w, unsigned short* __restrict__ out, int taps)
{
    const int e = blockIdx.x * 256 + threadIdx.x;
    const int kslot = e & 31;
    const int ocl   = (e >> 5) & 127;
    const int icc   = (e >> 12) & 7;
    const int oct   = (e >> 15) & 1;
    const int off   = e >> 16;
    const int oc = oct * 128 + ocl;
    const int q  = kslot >> 3, j = kslot & 7;
    const int ic = icc * 32 + ((q ^ ((ocl >> 2) & 3)) << 3) + j;
    out[e] = f2bf(w[((size_t)oc * C + ic) * taps + off]);
}

// ---------------------------------------------------------------------------
// pack the four 1x1 weight matrices in ONE launch.  grid = 1024
// ---------------------------------------------------------------------------
__global__ __launch_bounds__(256) void pack4_k(
    const float* __restrict__ wq, const float* __restrict__ wk,
    const float* __restrict__ wv, const float* __restrict__ wp,
    unsigned short* __restrict__ oq, unsigned short* __restrict__ ok,
    unsigned short* __restrict__ ov, unsigned short* __restrict__ op)
{
    const int bid  = blockIdx.x;
    const int wsel = bid >> 8;
    const int e    = (bid & 255) * 256 + threadIdx.x;
    const float* w = (wsel == 0) ? wq : (wsel == 1) ? wk : (wsel == 2) ? wv : wp;
    unsigned short* out = (wsel == 0) ? oq : (wsel == 1) ? ok : (wsel == 2) ? ov : op;
    const int kslot = e & 31;
    const int ocl   = (e >> 5) & 127;
    const int icc   = (e >> 12) & 7;
    const int oct   = (e >> 15) & 1;
    const int oc = oct * 128 + ocl;
    const int q  = kslot >> 3, j = kslot & 7;
    const int ic = icc * 32 + ((q ^ ((ocl >> 2) & 3)) << 3) + j;
    out[e] = f2bf(w[(size_t)oc * C + ic]);
}

// ---------------------------------------------------------------------------
// Fused dual 3x3 conv (IEM + NEM), BK=64, r3 single-buffer barrier structure.
// BN sum/sumsq fused contention-free (LDS reduce + per-block slot store).
// Block: 256 thr = 4 waves (2x2), tile 128oc x 128px. grid = 2048 (swizzled).
// launch_bounds(256,2): measured optimum.  (256,3) squeezed VGPRs (96->84,
// scratch spills: FETCH 73->234MB, WRITE 135->271MB) and diluted L2 tap
// reuse -> 309->381us regression.  2 blocks/CU is this kernel's sweet spot.
// ---------------------------------------------------------------------------
__global__ __launch_bounds__(256, 2) void conv2_k(
    const unsigned short* __restrict__ xT,
    const unsigned short* __restrict__ Wp0, const unsigned short* __restrict__ Wp1,
    unsigned short* __restrict__ out0, unsigned short* __restrict__ out1,
    const unsigned short* __restrict__ zbuf, float* __restrict__ stats_part)
{
    __shared__ unsigned short As[2][2][128 * 32];   // [set][kc]  32KB
    __shared__ unsigned short Bs[2][128 * 32];      // [kc]       16KB
    __shared__ float sstat[2][128][2];              // [set][loc][sum|ssq] 2KB

    const int id  = swz2048(blockIdx.x);
    const int oct = id & 1;
    const int ch  = (id >> 1) & 1;
    const int r   = (id >> 2) & 255;
    const int b   = id >> 10;
    const int px0 = ch * 128;

    const int t  = threadIdx.x;
    const int wv = t >> 6;
    const int l  = t & 63;
    const int wm = (wv >> 1) * 64;
    const int wn = (wv & 1) * 64;

    // zero stats LDS (first K-loop barrier orders this before epilogue use)
    ((float*)sstat)[t]       = 0.f;
    ((float*)sstat)[t + 256] = 0.f;

    // swizzled quad for frag reads
    const int qp = (l >> 4) ^ ((l >> 2) & 3);
    int a_off[4], b_off[4];
#pragma unroll
    for (int i = 0; i < 4; i++) {
        a_off[i] = (wm + i * 16 + (l & 15)) * 64 + qp * 16;   // bytes
        b_off[i] = (wn + i * 16 + (l & 15)) * 64 + qp * 16;
    }
    // B staging: lane l stages LDS slot row px=(wv*32+i*16+(l>>2)), quad (l&3)
    const int spx_base = wv * 32 + (l >> 2);
    const int skk0 = (((l & 3) ^ (l >> 4)) << 3);            // source k-group (elems)

    // valid taps are a contiguous range (block-uniform)
    const int off_lo = (r == 0) ? 3 : 0;
    const int off_hi = (r == 255) ? 6 : 9;

    f32x4 acc[2][4][4];
#pragma unroll
    for (int s = 0; s < 2; s++)
#pragma unroll
        for (int i = 0; i < 4; i++)
#pragma unroll
            for (int j = 0; j < 4; j++) acc[s][i][j] = (f32x4){0.f, 0.f, 0.f, 0.f};

#pragma unroll 1
    for (int off = off_lo; off < off_hi; ++off) {
        const int dy = off / 3, dx = off - dy * 3;
        const int rr = r + dy - 1;            // in [0,255] by construction
        const size_t rowpix = (size_t)(b * HW) + (size_t)rr * W;
#pragma unroll 1
        for (int ip = 0; ip < 4; ++ip) {      // icc pair: icc = 2*ip, 2*ip+1
            __syncthreads();   // previous pair's frag reads done
            // ---- stage A both sets, both kc (icc pair = 16KB contiguous) ----
            const size_t wofs = ((size_t)(((off * 2 + oct) * 8 + ip * 2)) * 4096) * 2
                                + wv * 2048 + l * 16;
#pragma unroll
            for (int kc = 0; kc < 2; kc++) {
                char* A0 = (char*)As[0][kc] + wv * 2048;
                char* A1 = (char*)As[1][kc] + wv * 2048;
                const size_t o = wofs + (size_t)kc * 8192;
                gld_lds16((const char*)Wp0 + o, A0);
                gld_lds16((const char*)Wp0 + o + 1024, A0 + 1024);
                gld_lds16((const char*)Wp1 + o, A1);
                gld_lds16((const char*)Wp1 + o + 1024, A1 + 1024);
                // ---- stage B (shared by both sets) ----
                const int ic0 = (ip * 2 + kc) * 32;
                char* BsB = (char*)Bs[kc] + wv * 2048;
#pragma unroll
                for (int i = 0; i < 2; i++) {
                    const int px = spx_base + i * 16;
                    const int cx = px0 + px + dx - 1;
                    const void* g = ((unsigned)cx > 255u)
                        ? (const void*)zbuf
                        : (const void*)(xT + ((rowpix + cx) * C + ic0 + skk0));
                    gld_lds16(g, BsB + i * 1024);
                }
            }
            asm volatile("s_waitcnt vmcnt(0)" ::: "memory");
            __syncthreads();
            // ---- fragments + 64 MFMAs (2 kc x 2 sets x 16) ----
#pragma unroll
            for (int kc = 0; kc < 2; kc++) {
                bf16x8 af0[4], af1[4], bfr[4];
#pragma unroll
                for (int i = 0; i < 4; i++) {
                    af0[i] = *(const bf16x8*)((const char*)As[0][kc] + a_off[i]);
                    af1[i] = *(const bf16x8*)((const char*)As[1][kc] + a_off[i]);
                }
#pragma unroll
                for (int i = 0; i < 4; i++)
                    bfr[i] = *(const bf16x8*)((const char*)Bs[kc] + b_off[i]);
#pragma unroll
                for (int mi = 0; mi < 4; mi++)
#pragma unroll
                    for (int nj = 0; nj < 4; nj++) {
                        acc[0][mi][nj] = __builtin_amdgcn_mfma_f32_16x16x32_bf16(
                            af0[mi], bfr[nj], acc[0][mi][nj], 0, 0, 0);
                        acc[1][mi][nj] = __builtin_amdgcn_mfma_f32_16x16x32_bf16(
                            af1[mi], bfr[nj], acc[1][mi][nj], 0, 0, 0);
                    }
            }
        }
    }

    // ---- epilogue: NCHW bf16 stores + LDS-reduced BN partials ----
    const int colpx = px0 + wn + (l & 15);
    const int rowoc = oct * 128 + wm + (l >> 4) * 4;
#pragma unroll
    for (int s = 0; s < 2; s++) {
        unsigned short* ob = s ? out1 : out0;
#pragma unroll
        for (int mi = 0; mi < 4; mi++) {
#pragma unroll
            for (int rg = 0; rg < 4; rg++) {
                const int oc = rowoc + mi * 16 + rg;
                float ps = 0.f, pq = 0.f;
#pragma unroll
                for (int nj = 0; nj < 4; nj++) {
                    const float v = acc[s][mi][nj][rg];
                    ps += v;
                    pq = fmaf(v, v, pq);
                    const int px = colpx + nj * 16;
                    const size_t idx = ((size_t)(b * C + oc)) * HW + (size_t)r * W + px;
                    ob[idx] = f2bf(v);
                }
                // reduce over the 16 px-lanes (same oc for all l&15)
                ps += __shfl_xor(ps, 1);  pq += __shfl_xor(pq, 1);
                ps += __shfl_xor(ps, 2);  pq += __shfl_xor(pq, 2);
                ps += __shfl_xor(ps, 4);  pq += __shfl_xor(pq, 4);
                ps += __shfl_xor(ps, 8);  pq += __shfl_xor(pq, 8);
                if ((l & 15) == 0) {
                    const int loc = wm + (l >> 4) * 4 + mi * 16 + rg;  // 0..127
                    atomicAdd(&sstat[s][loc][0], ps);
                    atomicAdd(&sstat[s][loc][1], pq);
                }
            }
        }
    }
    __syncthreads();
    // one coalesced 2KB store: entry t = s*128 + loc
    stats_part[(size_t)id * 512 + t * 2 + 0] = ((float(*)[2])sstat)[t][0];
    stats_part[(size_t)id * 512 + t * 2 + 1] = ((float(*)[2])sstat)[t][1];
}

// ---------------------------------------------------------------------------
// BN reduce + finalize: sum stats_part over the 1024 matching block slots
// per (set, oc), then emit fused scale/shift.  grid = 512 (s*256 + oc).
// ---------------------------------------------------------------------------
__global__ __launch_bounds__(256) void bn_reduce_k(
    const float* __restrict__ stats_part,
    const float* __restrict__ g0, const float* __restrict__ b0,
    const float* __restrict__ g1, const float* __restrict__ b1,
    float* __restrict__ scl0, float* __restrict__ shf0,
    float* __restrict__ scl1, float* __restrict__ shf1)
{
    const int s   = blockIdx.x >> 8;
    const int gc  = blockIdx.x & 255;
    const int oct = gc >> 7;
    const int loc = gc & 127;
    const int t   = threadIdx.x;
    const int ent = (s * 128 + loc) * 2;

    float ps = 0.f, pq = 0.f;
#pragma unroll
    for (int m = 0; m < 4; m++) {
        const int id = oct + 2 * (t + 256 * m);   // ids with id&1 == oct
        ps += stats_part[(size_t)id * 512 + ent];
        pq += stats_part[(size_t)id * 512 + ent + 1];
    }
    __shared__ float rs[256], rq[256];
    rs[t] = ps; rq[t] = pq;
    __syncthreads();
    for (int o = 128; o > 0; o >>= 1) {
        if (t < o) { rs[t] += rs[t + o]; rq[t] += rq[t + o]; }
        __syncthreads();
    }
    if (t == 0) {
        const float n    = (float)Bn * HW;
        const float mean = rs[0] / n;
        const float var  = rq[0] / n - mean * mean;
        const float g    = s ? g1[gc] : g0[gc];
        const float be   = s ? b1[gc] : b0[gc];
        const float sc   = g * rsqrtf(var + 1e-5f);
        if (s) { scl1[gc] = sc; shf1[gc] = be - mean * sc; }
        else   { scl0[gc] = sc; shf0[gc] = be - mean * sc; }
    }
}

// ---------------------------------------------------------------------------
// Fused dual 1x1 GEMM (Q + K).  BK=64, single-buffer.
// Block: 256 thr = 4 waves (2x2), tile 128oc x 128px. grid = 2048 (swizzled).
// LDS 64KB -> 2 blocks/CU max.
// ---------------------------------------------------------------------------
__global__ __launch_bounds__(256, 2) void gemm2_k(
    const unsigned short* __restrict__ qin, const unsigned short* __restrict__ kin,
    const unsigned short* __restrict__ Wpq, const unsigned short* __restrict__ Wpk,
    unsigned short* __restrict__ outq, unsigned short* __restrict__ outk)
{
    __shared__ unsigned short As[2][2][128 * 32];   // [set][kc] 32KB
    __shared__ unsigned short Bs[2][2][128 * 32];   // [set][kc] 32KB

    const int id  = swz2048(blockIdx.x);
    const int oct = id & 1;
    const int ch  = (id >> 1) & 1;
    const int r   = (id >> 2) & 255;
    const int b   = id >> 10;
    const int px0 = ch * 128;

    const int t  = threadIdx.x;
    const int wv = t >> 6;
    const int l  = t & 63;
    const int wm = (wv >> 1) * 64;
    const int wn = (wv & 1) * 64;

    const int qp = (l >> 4) ^ ((l >> 2) & 3);
    int a_off[4], b_off[4];
#pragma unroll
    for (int i = 0; i < 4; i++) {
        a_off[i] = (wm + i * 16 + (l & 15)) * 64 + qp * 16;
        b_off[i] = (wn + i * 16 + (l & 15)) * 64 + qp * 16;
    }
    const int spx_base = wv * 32 + (l >> 2);
    const int skk0 = (((l & 3) ^ (l >> 4)) << 3);

    const size_t rowpix = (size_t)(b * HW) + (size_t)r * W;

    f32x4 acc[2][4][4];
#pragma unroll
    for (int s = 0; s < 2; s++)
#pragma unroll
        for (int i = 0; i < 4; i++)
#pragma unroll
            for (int j = 0; j < 4; j++) acc[s][i][j] = (f32x4){0.f, 0.f, 0.f, 0.f};

#pragma unroll 1
    for (int ip = 0; ip < 4; ++ip) {
        __syncthreads();
#pragma unroll
        for (int kc = 0; kc < 2; kc++) {
            const int icc = ip * 2 + kc;
            const size_t wofs = ((size_t)(oct * 8 + icc) * 4096) * 2 + wv * 2048 + l * 16;
            char* Aq = (char*)As[0][kc] + wv * 2048;
            char* Ak = (char*)As[1][kc] + wv * 2048;
            gld_lds16((const char*)Wpq + wofs, Aq);
            gld_lds16((const char*)Wpq + wofs + 1024, Aq + 1024);
            gld_lds16((const char*)Wpk + wofs, Ak);
            gld_lds16((const char*)Wpk + wofs + 1024, Ak + 1024);
            const int ic0 = icc * 32;
            char* Bq = (char*)Bs[0][kc] + wv * 2048;
            char* Bk = (char*)Bs[1][kc] + wv * 2048;
#pragma unroll
            for (int i = 0; i < 2; i++) {
                const int cx = px0 + spx_base + i * 16;
                gld_lds16((const void*)(qin + ((rowpix + cx) * C + ic0 + skk0)), Bq + i * 1024);
                gld_lds16((const void*)(kin + ((rowpix + cx) * C + ic0 + skk0)), Bk + i * 1024);
            }
        }
        asm volatile("s_waitcnt vmcnt(0)" ::: "memory");
        __syncthreads();
#pragma unroll
        for (int kc = 0; kc < 2; kc++) {
#pragma unroll
            for (int s = 0; s < 2; s++) {
                bf16x8 af[4], bfr[4];
#pragma unroll
                for (int i = 0; i < 4; i++) {
                    af[i]  = *(const bf16x8*)((const char*)As[s][kc] + a_off[i]);
                    bfr[i] = *(const bf16x8*)((const char*)Bs[s][kc] + b_off[i]);
                }
#pragma unroll
                for (int mi = 0; mi < 4; mi++)
#pragma unroll
                    for (int nj = 0; nj < 4; nj++)
                        acc[s][mi][nj] = __builtin_amdgcn_mfma_f32_16x16x32_bf16(
                            af[mi], bfr[nj], acc[s][mi][nj], 0, 0, 0);
            }
        }
    }

    // ---- epilogue: NHWC bf16 for both outputs ----
    const int colpx = px0 + wn + (l & 15);
    const int rowoc = oct * 128 + wm + (l >> 4) * 4;
    const size_t pxg = (size_t)(b * HW) + (size_t)r * W;
#pragma unroll
    for (int s = 0; s < 2; s++) {
        unsigned short* ob = s ? outk : outq;
#pragma unroll
        for (int mi = 0; mi < 4; mi++) {
#pragma unroll
            for (int nj = 0; nj < 4; nj++) {
                __attribute__((aligned(8))) unsigned short rv[4];
#pragma unroll
                for (int rg = 0; rg < 4; rg++) rv[rg] = f2bf(acc[s][mi][nj][rg]);
                const int oc = rowoc + mi * 16;
                const int px = colpx + nj * 16;
                *(uint2*)(ob + (pxg + px) * C + oc) = *(const uint2*)rv;
            }
        }
    }
}

// ---------------------------------------------------------------------------
// MFMA GEMM (1x1 conv, K = 256), BK=64 single-buffer (4 barrier-pairs).
// B input: NHWC bf16.  Output: NCHW fp32 / NHWC bf16.
// Block: 256 thr = 4 waves (2x2), tile 128oc x 128px. grid = 2048 (swizzled).
// launch_bounds(256,4): 32KB LDS x4 = 128KB, 56 VGPR -> no squeeze; ~12us
// net gain measured r10.
// ---------------------------------------------------------------------------
template<bool F32OUT, bool NHWC_OUT>
__global__ __launch_bounds__(256, 4) void gemm_k(
    const unsigned short* __restrict__ xT, const unsigned short* __restrict__ Wp,
    unsigned short* __restrict__ outb, float* __restrict__ outf)
{
    __shared__ unsigned short As[2][128 * 32];   // [kc] 16KB
    __shared__ unsigned short Bs[2][128 * 32];   // [kc] 16KB

    const int id  = swz2048(blockIdx.x);
    const int oct = id & 1;
    const int ch  = (id >> 1) & 1;
    const int r   = (id >> 2) & 255;
    const int b   = id >> 10;
    const int px0 = ch * 128;

    const int t  = threadIdx.x;
    const int wv = t >> 6;
    const int l  = t & 63;
    const int wm = (wv >> 1) * 64;
    const int wn = (wv & 1) * 64;

    const int qp = (l >> 4) ^ ((l >> 2) & 3);
    int a_off[4], b_off[4];
#pragma unroll
    for (int i = 0; i < 4; i++) {
        a_off[i] = (wm + i * 16 + (l & 15)) * 64 + qp * 16;
        b_off[i] = (wn + i * 16 + (l & 15)) * 64 + qp * 16;
    }
    const int spx_base = wv * 32 + (l >> 2);
    const int skk0 = (((l & 3) ^ (l >> 4)) << 3);

    const size_t rowpix = (size_t)(b * HW) + (size_t)r * W;

    f32x4 acc[4][4];
#pragma unroll
    for (int i = 0; i < 4; i++)
#pragma unroll
        for (int j = 0; j < 4; j++) acc[i][j] = (f32x4){0.f, 0.f, 0.f, 0.f};

#pragma unroll 1
    for (int ip = 0; ip < 4; ++ip) {
        __syncthreads();
#pragma unroll
        for (int kc = 0; kc < 2; kc++) {
            const int icc = ip * 2 + kc;
            const char* Ag = (const char*)Wp +
                ((size_t)(oct * 8 + icc) * 4096) * 2 + wv * 2048 + l * 16;
            char* AsB = (char*)As[kc] + wv * 2048;
            gld_lds16(Ag, AsB);
            gld_lds16(Ag + 1024, AsB + 1024);
            const int ic0 = icc * 32;
            char* BsB = (char*)Bs[kc] + wv * 2048;
#pragma unroll
            for (int i = 0; i < 2; i++) {
                const int cx = px0 + spx_base + i * 16;
                gld_lds16((const void*)(xT + ((rowpix + cx) * C + ic0 + skk0)), BsB + i * 1024);
            }
        }
        asm volatile("s_waitcnt vmcnt(0)" ::: "memory");
        __syncthreads();
#pragma unroll
        for (int kc = 0; kc < 2; kc++) {
            bf16x8 af[4], bfr[4];
#pragma unroll
            for (int i = 0; i < 4; i++) {
                af[i]  = *(const bf16x8*)((const char*)As[kc] + a_off[i]);
                bfr[i] = *(const bf16x8*)((const char*)Bs[kc] + b_off[i]);
            }
#pragma unroll
            for (int mi = 0; mi < 4; mi++)
#pragma unroll
                for (int nj = 0; nj < 4; nj++)
                    acc[mi][nj] = __builtin_amdgcn_mfma_f32_16x16x32_bf16(
                        af[mi], bfr[nj], acc[mi][nj], 0, 0, 0);
        }
    }

    // ---- epilogue: C/D layout col=lane&15, row=(lane>>4)*4+reg ----
    const int colpx = px0 + wn + (l & 15);
    const int rowoc = oct * 128 + wm + (l >> 4) * 4;
    if (NHWC_OUT) {
        const size_t pxg = (size_t)(b * HW) + (size_t)r * W;
#pragma unroll
        for (int mi = 0; mi < 4; mi++) {
#pragma unroll
            for (int nj = 0; nj < 4; nj++) {
                __attribute__((aligned(8))) unsigned short rv[4];
#pragma unroll
                for (int rg = 0; rg < 4; rg++) rv[rg] = f2bf(acc[mi][nj][rg]);
                const int oc = rowoc + mi * 16;
                const int px = colpx + nj * 16;
                *(uint2*)(outb + (pxg + px) * C + oc) = *(const uint2*)rv;
            }
        }
    } else {
#pragma unroll
        for (int mi = 0; mi < 4; mi++) {
#pragma unroll
            for (int nj = 0; nj < 4; nj++) {
#pragma unroll
                for (int rg = 0; rg < 4; rg++) {
                    const int oc = rowoc + mi * 16 + rg;
                    const int px = colpx + nj * 16;
                    const size_t idx = ((size_t)(b * C + oc)) * HW + (size_t)r * W + px;
                    if (F32OUT) outf[idx] = acc[mi][nj][rg];
                    else        outb[idx] = f2bf(acc[mi][nj][rg]);
                }
            }
        }
    }
}

// ---------------------------------------------------------------------------
// depthwise 3x3 with BN+relu6 fused on input read + fused per-pixel channel
// mean partials.  MERGED IEM+NEM, 32-channel blocks (27KB LDS, 5-6 blk/CU).
// In: NCHW bf16 conv raw (per set).  Out: NHWC bf16 + smean fp32 [B*HW].
// grid = 32768: c0=(id&7)*32, w0=((id>>3)&3)*64, r=(id>>5)&255,
//               b=(id>>13)&1, set=id>>14
// ---------------------------------------------------------------------------
__global__ __launch_bounds__(256) void dwconv_k(
    const unsigned short* __restrict__ a0, const unsigned short* __restrict__ a1,
    const float* __restrict__ scl0, const float* __restrict__ shf0,
    const float* __restrict__ scl1, const float* __restrict__ shf1,
    const float* __restrict__ wd0, const float* __restrict__ wd1,
    unsigned short* __restrict__ out0, unsigned short* __restrict__ out1,
    float* __restrict__ sm0, float* __restrict__ sm1)
{
    __shared__ float tile[32][3][67];   // cols w0-1 .. w0+65 -> idx 0..65
    __shared__ float wds[32 * 9];
    __shared__ float sscl[32], sshf[32];

    const int id  = blockIdx.x;
    const int c0  = (id & 7) * 32;
    const int w0  = ((id >> 3) & 3) * 64;
    const int r   = (id >> 5) & 255;
    const int b   = (id >> 13) & 1;
    const int set = id >> 14;
    const int t   = threadIdx.x;

    const unsigned short* a   = set ? a1 : a0;
    const float* scale        = set ? scl1 : scl0;
    const float* shift        = set ? shf1 : shf0;
    const float* wd           = set ? wd1 : wd0;
    unsigned short* out       = set ? out1 : out0;
    float* smean              = set ? sm1 : sm0;

    for (int i = t; i < 288; i += 256) wds[i] = wd[c0 * 9 + i];
    if (t < 32) { sscl[t] = scale[c0 + t]; sshf[t] = shift[c0 + t]; }
    __syncthreads();

    // main staging: 32c x 3row x 16seg of 4 elems (1536 items, 6 per thread)
    for (int i = t; i < 1536; i += 256) {
        const int c   = i / 48;
        const int rem = i - c * 48;
        const int row = rem >> 4, seg = rem & 15;
        const int rr  = r + row - 1;
        float f0 = 0.f, f1 = 0.f, f2 = 0.f, f3 = 0.f;
        if ((unsigned)rr < 256u) {
            const uint2 v = *(const uint2*)(a + ((size_t)(b * C + c0 + c)) * HW
                                              + (size_t)rr * W + w0 + seg * 4);
            const float sc = sscl[c], sh = sshf[c];
            f0 = fminf(fmaxf(fmaf(bflo(v.x), sc, sh), 0.f), 6.f);
            f1 = fminf(fmaxf(fmaf(bfhi(v.x), sc, sh), 0.f), 6.f);
            f2 = fminf(fmaxf(fmaf(bflo(v.y), sc, sh), 0.f), 6.f);
            f3 = fminf(fmaxf(fmaf(bfhi(v.y), sc, sh), 0.f), 6.f);
        }
        float* dst = &tile[c][row][1 + seg * 4];
        dst[0] = f0; dst[1] = f1; dst[2] = f2; dst[3] = f3;
    }
    // edges: 32c x 3row x 2side (192 items)
    for (int i = t; i < 192; i += 256) {
        const int c   = i / 6;
        const int rem = i - c * 6;
        const int row = rem >> 1, side = rem & 1;
        const int rr  = r + row - 1;
        const int col = side ? (w0 + 64) : (w0 - 1);
        float v = 0.f;
        if ((unsigned)rr < 256u && (unsigned)col < 256u) {
            float u = bf2f(a[((size_t)(b * C + c0 + c)) * HW + (size_t)rr * W + col]);
            v = fminf(fmaxf(fmaf(u, sscl[c], sshf[c]), 0.f), 6.f);
        }
        tile[c][row][side ? 65 : 0] = v;
    }
    __syncthreads();

    const int px = t >> 2, csub = t & 3;
    __attribute__((aligned(16))) unsigned short res[8];
    float psum = 0.f;
#pragma unroll
    for (int k = 0; k < 8; k++) {
        const int c = csub * 8 + k;
        const float* wp = &wds[c * 9];
        float accv = 0.f;
#pragma unroll
        for (int dy = 0; dy < 3; dy++)
#pragma unroll
            for (int dx = 0; dx < 3; dx++)
                accv = fmaf(tile[c][dy][px + dx], wp[dy * 3 + dx], accv);
        res[k] = f2bf(accv);
        psum += accv;
    }
    unsigned short* o = out + ((size_t)(b * HW) + (size_t)r * W + w0 + px) * C + c0 + csub * 8;
    *(uint4*)o = *(const uint4*)&res[0];

    // fused channel-mean partial: quad-reduce (lanes t, t^1, t^2 share px)
    psum += __shfl_xor(psum, 1);
    psum += __shfl_xor(psum, 2);
    if (csub == 0)
        atomicAdd(&smean[(size_t)(b * HW) + (size_t)r * W + w0 + px], psum * (1.f / C));
}

// ---------------------------------------------------------------------------
// windowed attention via MFMA. One wave per (b, head, wy, wx) window.
// q,k,v: NHWC bf16.  out: NHWC bf16.  setprio(1) around MFMA clusters (T5).
// ---------------------------------------------------------------------------
__global__ __launch_bounds__(64) void attn_k(
    const unsigned short* __restrict__ q, const unsigned short* __restrict__ k,
    const unsigned short* __restrict__ v, const float* __restrict__ si,
    const float* __restrict__ sn, const float* __restrict__ temp,
    unsigned short* __restrict__ out)
{
    __shared__ unsigned short Pl[64][72];   // P rows: pitch 144B (16B aligned)
    __shared__ unsigned short Vt[32][72];   // V^T rows: [d][kpix]

    const int id   = blockIdx.x;
    const int wx   = id & 31;
    const int wy   = (id >> 5) & 31;
    const int head = (id >> 10) & 7;
    const int b    = id >> 13;
    const int l    = threadIdx.x;
    const int pl15 = l & 15;
    const int g    = l >> 4;
    const int ch0  = head * 32;
    const int base = wy * 8 * W + wx * 8;       // window origin pixel
    const size_t bb = (size_t)b * HW;

    // ---- load Q/K fragments (A-frag layout: row=lane&15, kgrp=lane>>4) ----
    uint4 qv[4], kv[4];
    float qss[4], kss[4];
#pragma unroll
    for (int i = 0; i < 4; i++) {
        const int p = i * 16 + pl15;
        const size_t a = (bb + base + (p >> 3) * W + (p & 7)) * C + ch0 + g * 8;
        qv[i] = *(const uint4*)(q + a);
        kv[i] = *(const uint4*)(k + a);
        // partial squared norms over this lane's 8 channels
        float s0 = 0.f, s1 = 0.f;
        {
            uint4 u = qv[i];
            float f;
            f = bflo(u.x); s0 = fmaf(f, f, s0);  f = bfhi(u.x); s0 = fmaf(f, f, s0);
            f = bflo(u.y); s0 = fmaf(f, f, s0);  f = bfhi(u.y); s0 = fmaf(f, f, s0);
            f = bflo(u.z); s0 = fmaf(f, f, s0);  f = bfhi(u.z); s0 = fmaf(f, f, s0);
            f = bflo(u.w); s0 = fmaf(f, f, s0);  f = bfhi(u.w); s0 = fmaf(f, f, s0);
        }
        {
            uint4 u = kv[i];
            float f;
            f = bflo(u.x); s1 = fmaf(f, f, s1);  f = bfhi(u.x); s1 = fmaf(f, f, s1);
            f = bflo(u.y); s1 = fmaf(f, f, s1);  f = bfhi(u.y); s1 = fmaf(f, f, s1);
            f = bflo(u.z); s1 = fmaf(f, f, s1);  f = bfhi(u.z); s1 = fmaf(f, f, s1);
            f = bflo(u.w); s1 = fmaf(f, f, s1);  f = bfhi(u.w); s1 = fmaf(f, f, s1);
        }
        // full 32-ch norms: combine the 4 d-groups (lanes l, l^16, l^32, l^48)
        s0 += __shfl_xor(s0, 16); s0 += __shfl_xor(s0, 32);
        s1 += __shfl_xor(s1, 16); s1 += __shfl_xor(s1, 32);
        qss[i] = s0; kss[i] = s1;
    }

    // ---- stage V^T into LDS: lane l owns window pixel l (32 scalar writes) ----
    {
        const size_t a = (bb + base + (l >> 3) * W + (l & 7)) * C + ch0;
        const uint4* vp = (const uint4*)(v + a);
#pragma unroll
        for (int i = 0; i < 4; i++) {
            uint4 vv = vp[i];
            Vt[i * 8 + 0][l] = (unsigned short)(vv.x);
            Vt[i * 8 + 1][l] = (unsigned short)(vv.x >> 16);
            Vt[i * 8 + 2][l] = (unsigned short)(vv.y);
            Vt[i * 8 + 3][l] = (unsigned short)(vv.y >> 16);
            Vt[i * 8 + 4][l] = (unsigned short)(vv.z);
            Vt[i * 8 + 5][l] = (unsigned short)(vv.z >> 16);
            Vt[i * 8 + 6][l] = (unsigned short)(vv.w);
            Vt[i * 8 + 7][l] = (unsigned short)(vv.w >> 16);
        }
    }

    // ---- per-pixel scales ----
    const float tsc = temp[head] * 0.17677669529663689f;   // 32^-0.5
    float qmul[4], kscl[4];
#pragma unroll
    for (int i = 0; i < 4; i++) {
        const int p = i * 16 + pl15;
        const size_t pg = bb + base + (p >> 3) * W + (p & 7);
        const float il = si[pg];
        const float nz = sn[pg];
        qmul[i] = (1.f + il) * tsc / fmaxf(sqrtf(qss[i]), 1e-12f);
        kscl[i] = fminf(fmaxf(1.f - nz, 0.f), 1.f) / fmaxf(sqrtf(kss[i]), 1e-12f);
    }

    // ---- S = Q * K^T: 16 MFMAs ----
    f32x4 acc[4][4];
    __builtin_amdgcn_s_setprio(1);
#pragma unroll
    for (int qi = 0; qi < 4; qi++)
#pragma unroll
        for (int kj = 0; kj < 4; kj++)
            acc[qi][kj] = __builtin_amdgcn_mfma_f32_16x16x32_bf16(
                u2b(qv[qi]), u2b(kv[kj]), (f32x4){0.f, 0.f, 0.f, 0.f}, 0, 0, 0);
    __builtin_amdgcn_s_setprio(0);

    // ---- scale + softmax (rows owned: q = qi*16 + g*4 + rg) + P -> LDS ----
    float inv[4][4];
#pragma unroll
    for (int qi = 0; qi < 4; qi++) {
#pragma unroll
        for (int rg = 0; rg < 4; rg++) {
            const float qm = __shfl(qmul[qi], (g << 2) + rg);
            float s[4];
#pragma unroll
            for (int kj = 0; kj < 4; kj++) s[kj] = acc[qi][kj][rg] * kscl[kj] * qm;
            float mx = fmaxf(fmaxf(s[0], s[1]), fmaxf(s[2], s[3]));
            mx = fmaxf(mx, __shfl_xor(mx, 1));
            mx = fmaxf(mx, __shfl_xor(mx, 2));
            mx = fmaxf(mx, __shfl_xor(mx, 4));
            mx = fmaxf(mx, __shfl_xor(mx, 8));
            float sum = 0.f;
#pragma unroll
            for (int kj = 0; kj < 4; kj++) {
                const float e = __expf(s[kj] - mx);
                acc[qi][kj][rg] = e;
                sum += e;
            }
            sum += __shfl_xor(sum, 1);
            sum += __shfl_xor(sum, 2);
            sum += __shfl_xor(sum, 4);
            sum += __shfl_xor(sum, 8);
            inv[qi][rg] = 1.f / sum;
            const int qrow = qi * 16 + (g << 2) + rg;
#pragma unroll
            for (int kj = 0; kj < 4; kj++)
                Pl[qrow][pl15 + 16 * kj] = f2bf(acc[qi][kj][rg]);
        }
    }

    // ---- O = P * V: 16 MFMAs (K-dim = 64 k-pixels, 2 chunks of 32) ----
    f32x4 oacc[4][2];
#pragma unroll
    for (int qi = 0; qi < 4; qi++)
#pragma unroll
        for (int dj = 0; dj < 2; dj++) oacc[qi][dj] = (f32x4){0.f, 0.f, 0.f, 0.f};

#pragma unroll
    for (int kc = 0; kc < 2; kc++) {
        const bf16x8 vb0 = *(const bf16x8*)&Vt[pl15][kc * 32 + g * 8];
        const bf16x8 vb1 = *(const bf16x8*)&Vt[pl15 + 16][kc * 32 + g * 8];
        __builtin_amdgcn_s_setprio(1);
#pragma unroll
        for (int qi = 0; qi < 4; qi++) {
            const bf16x8 pa = *(const bf16x8*)&Pl[qi * 16 + pl15][kc * 32 + g * 8];
            oacc[qi][0] = __builtin_amdgcn_mfma_f32_16x16x32_bf16(pa, vb0, oacc[qi][0], 0, 0, 0);
            oacc[qi][1] = __builtin_amdgcn_mfma_f32_16x16x32_bf16(pa, vb1, oacc[qi][1], 0, 0, 0);
        }
        __builtin_amdgcn_s_setprio(0);
    }

    // ---- epilogue: row q = qi*16 + g*4 + rg, col d = pl15 + 16*dj ----
#pragma unroll
    for (int qi = 0; qi < 4; qi++) {
#pragma unroll
        for (int rg = 0; rg < 4; rg++) {
            const int qrow = qi * 16 + (g << 2) + rg;
            const size_t oaddr = (bb + base + (qrow >> 3) * W + (qrow & 7)) * C + ch0;
            const float sc = inv[qi][rg];
            out[oaddr + pl15]      = f2bf(oacc[qi][0][rg] * sc);
            out[oaddr + 16 + pl15] = f2bf(oacc[qi][1][rg] * sc);
        }
    }
}

// ---------------------------------------------------------------------------
extern "C" void kernel_launch(void* const* d_in, const int* in_sizes, int n_in,
                              void* d_out, int out_size, void* d_ws, size_t ws_size,
                              hipStream_t stream)
{
    const float* x        = (const float*)d_in[0];
    const float* w_iem    = (const float*)d_in[1];
    const float* g_iem    = (const float*)d_in[2];
    const float* b_iem    = (const float*)d_in[3];
    const float* w_nem    = (const float*)d_in[4];
    const float* g_nem    = (const float*)d_in[5];
    const float* b_nem    = (const float*)d_in[6];
    const float* w_iem_dw = (const float*)d_in[7];
    const float* w_nem_dw = (const float*)d_in[8];
    const float* w_q      = (const float*)d_in[9];
    const float* w_k      = (const float*)d_in[10];
    const float* w_v      = (const float*)d_in[11];
    const float* w_proj   = (const float*)d_in[12];
    const float* temp     = (const float*)d_in[13];

    // workspace carve-up (bytes)
    char* p = (char*)d_ws;
    unsigned short* zbuf = (unsigned short*)p;      p += 256;
    float* scl0 = (float*)p;                        p += 256 * 4;
    float* shf0 = (float*)p;                        p += 256 * 4;
    float* scl1 = (float*)p;                        p += 256 * 4;
    float* shf1 = (float*)p;                        p += 256 * 4;
    float* stats_part = (float*)p;                  p += (size_t)2048 * 512 * 4;  // 4MB
    float* sI  = (float*)p;                         p += (size_t)Bn * HW * 4;
    float* sN  = (float*)p;                         p += (size_t)Bn * HW * 4;
    unsigned short* Wp_iem = (unsigned short*)p;    p += 589824 * 2;
    unsigned short* Wp_nem = (unsigned short*)p;    p += 589824 * 2;
    unsigned short* Wpq = (unsigned short*)p;       p += 65536 * 2;
    unsigned short* Wpk = (unsigned short*)p;       p += 65536 * 2;
    unsigned short* Wpv = (unsigned short*)p;       p += 65536 * 2;
    unsigned short* Wpp = (unsigned short*)p;       p += 65536 * 2;
    unsigned short* xT   = (unsigned short*)p;      p += Bn * CHW * 2;  // NHWC bf16
    unsigned short* bufA = (unsigned short*)p;      p += Bn * CHW * 2;  // IEM raw (NCHW) / Q (NHWC)
    unsigned short* Ibf  = (unsigned short*)p;      p += Bn * CHW * 2;  // illum NHWC / attn out NHWC
    unsigned short* Nbf  = (unsigned short*)p;      p += Bn * CHW * 2;  // noise NHWC / V (NHWC)
    unsigned short* Obf  = (unsigned short*)p;      p += Bn * CHW * 2;  // NEM raw (NCHW) / K (NHWC)

    hipMemsetAsync(zbuf, 0, 256, stream);
    hipMemsetAsync(sI, 0, (size_t)Bn * HW * 4 * 2, stream);   // sI + sN contiguous

    packx_k<<<8192, 256, 0, stream>>>(x, xT);
    pack_k<<<2304, 256, 0, stream>>>(w_iem, Wp_iem, 9);
    pack_k<<<2304, 256, 0, stream>>>(w_nem, Wp_nem, 9);
    pack4_k<<<1024, 256, 0, stream>>>(w_q, w_k, w_v, w_proj, Wpq, Wpk, Wpv, Wpp);

    // fused IEM+NEM 3x3 conv + contention-free BN partials
    conv2_k<<<2048, 256, 0, stream>>>(xT, Wp_iem, Wp_nem, bufA, Obf, zbuf, stats_part);
    bn_reduce_k<<<512, 256, 0, stream>>>(stats_part, g_iem, b_iem, g_nem, b_nem,
                                         scl0, shf0, scl1, shf1);

    // merged depthwise (both sets; BN+relu6 on read, channel-mean on write)
    dwconv_k<<<32768, 256, 0, stream>>>(bufA, Obf, scl0, shf0, scl1, shf1,
                                        w_iem_dw, w_nem_dw, Ibf, Nbf, sI, sN);

    // fused Q+K projections -> NHWC bf16 (Q->bufA, K->Obf)
    gemm2_k<<<2048, 256, 0, stream>>>(Ibf, Nbf, Wpq, Wpk, bufA, Obf);
    // V projection (Nbf consumed by gemm2 above)
    gemm_k<false, true><<<2048, 256, 0, stream>>>(xT, Wpv, Nbf, nullptr);

    attn_k<<<16384, 64, 0, stream>>>(bufA, Obf, Nbf, sI, sN, temp, Ibf);

    // final projection -> fp32 d_out (NCHW)
    gemm_k<true, false><<<2048, 256, 0, stream>>>(Ibf, Wpp, nullptr, (float*)d_out);
}

// Round 12
// 992.689 us; speedup vs baseline: 1.0783x; 1.0213x over previous
//
#include <hip/hip_runtime.h>
#include <math.h>

// ---------------------------------------------------------------------------
// Problem constants
constexpr int Bn  = 2;
constexpr int C   = 256;
constexpr int H   = 256;
constexpr int W   = 256;
constexpr int HW  = H * W;          // 65536
constexpr size_t CHW = (size_t)C * HW;

typedef __bf16 bf16x8 __attribute__((ext_vector_type(8)));
typedef float  f32x4  __attribute__((ext_vector_type(4)));

// fp32 -> bf16 round-to-nearest-even
__device__ __forceinline__ unsigned short f2bf(float f) {
    unsigned int u = __float_as_uint(f);
    u += 0x7fffu + ((u >> 16) & 1u);
    return (unsigned short)(u >> 16);
}
__device__ __forceinline__ float bf2f(unsigned short h) {
    return __uint_as_float(((unsigned int)h) << 16);
}
// two bf16 packed in a uint -> floats (hi needs only a mask)
__device__ __forceinline__ float bflo(unsigned int u) { return __uint_as_float(u << 16); }
__device__ __forceinline__ float bfhi(unsigned int u) { return __uint_as_float(u & 0xffff0000u); }

__device__ __forceinline__ bf16x8 u2b(uint4 u) {
    union { uint4 a; bf16x8 b; } c; c.a = u; return c.b;
}

// async global->LDS, 16B per lane; LDS dest = uniform base + lane*16
__device__ __forceinline__ void gld_lds16(const void* g, void* lds) {
    __builtin_amdgcn_global_load_lds(
        (const __attribute__((address_space(1))) unsigned int*)g,
        (__attribute__((address_space(3))) unsigned int*)lds, 16, 0, 0);
}

// XCD-aware bijective swizzle for 2048-block grids (2048 % 8 == 0)
__device__ __forceinline__ int swz2048(int bid) {
    return ((bid & 7) << 8) | (bid >> 3);
}

// ---------------------------------------------------------------------------
// packx: x fp32 NCHW -> bf16 NHWC.  Tile 64c x 64px via LDS transpose.
// grid = (2*65536/64) * 4 = 8192 blocks
// ---------------------------------------------------------------------------
__global__ __launch_bounds__(256) void packx_k(
    const float* __restrict__ x, unsigned short* __restrict__ xT)
{
    __shared__ float tl[64][65];
    const int id = blockIdx.x;
    const int ct = id & 3;
    const size_t px0 = (size_t)(id >> 2) * 64;   // global pixel (incl batch)
    const int b  = (int)(px0 >> 16);
    const int hw = (int)(px0 & 65535);
    const int c0 = ct * 64;
    const int t  = threadIdx.x;

    {   // load: thread (cl, pseg): 16 px of channel cl
        const int cl = t >> 2, pseg = t & 3;
        const float* src = x + ((size_t)(b * C + c0 + cl)) * HW + hw + pseg * 16;
#pragma unroll
        for (int i = 0; i < 4; i++) {
            float4 v = *(const float4*)(src + i * 4);
            tl[cl][pseg * 16 + i * 4 + 0] = v.x;
            tl[cl][pseg * 16 + i * 4 + 1] = v.y;
            tl[cl][pseg * 16 + i * 4 + 2] = v.z;
            tl[cl][pseg * 16 + i * 4 + 3] = v.w;
        }
    }
    __syncthreads();
    {   // store: thread (pl, csec): 16 channels of pixel pl, contiguous in NHWC
        const int pl = t >> 2, csec = t & 3;
        __attribute__((aligned(16))) unsigned short rv[16];
#pragma unroll
        for (int j = 0; j < 16; j++) rv[j] = f2bf(tl[csec * 16 + j][pl]);
        unsigned short* dst = xT + (px0 + pl) * C + c0 + csec * 16;
        *(uint4*)dst       = *(const uint4*)&rv[0];
        *(uint4*)(dst + 8) = *(const uint4*)&rv[8];
    }
}

// ---------------------------------------------------------------------------
// pack weights into the LDS image the GEMM stages:
// layout [taps][oct(2)][icc(8)][ocl(128)][kslot(32)], with XOR-4 swizzle
// ---------------------------------------------------------------------------
__global__ __launch_bounds__(256) void pack_k(
    const float* __restrict__ w, unsigned short* __restrict__ out, int taps)
{
    const int e = blockIdx.x * 256 + threadIdx.x;
    const int kslot = e & 31;
    const int ocl   = (e >> 5) & 127;
    const int icc   = (e >> 12) & 7;
    const int oct   = (e >> 15) & 1;
    const int off   = e >> 16;
    const int oc = oct * 128 + ocl;
    const int q  = kslot >> 3, j = kslot & 7;
    const int ic = icc * 32 + ((q ^ ((ocl >> 2) & 3)) << 3) + j;
    out[e] = f2bf(w[((size_t)oc * C + ic) * taps + off]);
}

// ---------------------------------------------------------------------------
// pack the four 1x1 weight matrices in ONE launch.  grid = 1024
// ---------------------------------------------------------------------------
__global__ __launch_bounds__(256) void pack4_k(
    const float* __restrict__ wq, const float* __restrict__ wk,
    const float* __restrict__ wv, const float* __restrict__ wp,
    unsigned short* __restrict__ oq, unsigned short* __restrict__ ok,
    unsigned short* __restrict__ ov, unsigned short* __restrict__ op)
{
    const int bid  = blockIdx.x;
    const int wsel = bid >> 8;
    const int e    = (bid & 255) * 256 + threadIdx.x;
    const float* w = (wsel == 0) ? wq : (wsel == 1) ? wk : (wsel == 2) ? wv : wp;
    unsigned short* out = (wsel == 0) ? oq : (wsel == 1) ? ok : (wsel == 2) ? ov : op;
    const int kslot = e & 31;
    const int ocl   = (e >> 5) & 127;
    const int icc   = (e >> 12) & 7;
    const int oct   = (e >> 15) & 1;
    const int oc = oct * 128 + ocl;
    const int q  = kslot >> 3, j = kslot & 7;
    const int ic = icc * 32 + ((q ^ ((ocl >> 2) & 3)) << 3) + j;
    out[e] = f2bf(w[(size_t)oc * C + ic]);
}

// ---------------------------------------------------------------------------
// Fused dual 3x3 conv (IEM + NEM) with HALO-SHARED B staging:
// per (dy, icc): stage B ONCE with 2-px halo (130 rows), stage A for the
// 3 dx-taps x 2 sets, then 96 MFMAs.  Barrier-pairs 36 -> 24, B staging /3.
// XOR-4 swizzle keyed on LDS row j both sides: stage kg=(l&3)^((j>>2)&3),
// read bq=g^((j>>2)&3), j=px+dx.
// BN sum/sumsq fused contention-free (LDS reduce + per-block slot store).
// Block: 256 thr = 4 waves (2x2), tile 128oc x 128px. grid = 2048 (swizzled).
// launch_bounds(256,2): measured optimum ((256,3) spills, r10).
// ---------------------------------------------------------------------------
__global__ __launch_bounds__(256, 2) void conv2_k(
    const unsigned short* __restrict__ xT,
    const unsigned short* __restrict__ Wp0, const unsigned short* __restrict__ Wp1,
    unsigned short* __restrict__ out0, unsigned short* __restrict__ out1,
    const unsigned short* __restrict__ zbuf, float* __restrict__ stats_part)
{
    __shared__ unsigned short As[3][2][128 * 32];   // [dxt][set]  48KB
    __shared__ unsigned short Bs[136 * 32];         // halo rows 0..129  8.5KB
    __shared__ float sstat[2][128][2];              // [set][loc][sum|ssq] 2KB

    const int id  = swz2048(blockIdx.x);
    const int oct = id & 1;
    const int ch  = (id >> 1) & 1;
    const int r   = (id >> 2) & 255;
    const int b   = id >> 10;
    const int px0 = ch * 128;

    const int t  = threadIdx.x;
    const int wv = t >> 6;
    const int l  = t & 63;
    const int wm = (wv >> 1) * 64;
    const int wn = (wv & 1) * 64;
    const int g  = l >> 4;

    // zero stats LDS (first K-loop barrier orders this before epilogue use)
    ((float*)sstat)[t]       = 0.f;
    ((float*)sstat)[t + 256] = 0.f;

    // A frag read offsets (swizzled quad, same as pack layout)
    const int qp = (l >> 4) ^ ((l >> 2) & 3);
    int a_off[4];
#pragma unroll
    for (int i = 0; i < 4; i++)
        a_off[i] = (wm + i * 16 + (l & 15)) * 64 + qp * 16;   // bytes

    // valid conv rows (block-uniform contiguous range of dy)
    const int dy_lo = (r == 0) ? 1 : 0;
    const int dy_hi = (r == 255) ? 1 : 2;

    f32x4 acc[2][4][4];
#pragma unroll
    for (int s = 0; s < 2; s++)
#pragma unroll
        for (int i = 0; i < 4; i++)
#pragma unroll
            for (int j = 0; j < 4; j++) acc[s][i][j] = (f32x4){0.f, 0.f, 0.f, 0.f};

#pragma unroll 1
    for (int dy = dy_lo; dy <= dy_hi; ++dy) {
        const int rr = r + dy - 1;            // in [0,255] by construction
        const size_t rowpix = (size_t)(b * HW) + (size_t)rr * W;
#pragma unroll 1
        for (int icc = 0; icc < 8; ++icc) {
            __syncthreads();   // previous chunk's frag reads done
            // ---- stage A: 3 dx-taps x 2 sets (8KB tiles) ----
#pragma unroll
            for (int dxt = 0; dxt < 3; dxt++) {
                const int off = dy * 3 + dxt;
                const size_t wofs = ((size_t)(((off * 2 + oct) * 8 + icc)) * 4096) * 2
                                    + wv * 2048 + l * 16;
                char* A0 = (char*)As[dxt][0] + wv * 2048;
                char* A1 = (char*)As[dxt][1] + wv * 2048;
                gld_lds16((const char*)Wp0 + wofs, A0);
                gld_lds16((const char*)Wp0 + wofs + 1024, A0 + 1024);
                gld_lds16((const char*)Wp1 + wofs, A1);
                gld_lds16((const char*)Wp1 + wofs + 1024, A1 + 1024);
            }
            // ---- stage B once, with halo (rows j=0..129, gpx = px0+j-1) ----
            const int ic0 = icc * 32;
#pragma unroll
            for (int i = 0; i < 2; i++) {
                const int j   = wv * 16 + (l >> 2) + i * 64;    // 0..127
                const int gpx = px0 + j - 1;
                const int kg  = (l & 3) ^ ((j >> 2) & 3);
                const void* gsrc = ((unsigned)gpx > 255u)
                    ? (const void*)zbuf
                    : (const void*)(xT + ((rowpix + gpx) * C + ic0 + kg * 8));
                gld_lds16(gsrc, (char*)Bs + wv * 1024 + i * 4096);
            }
            if (t < 8) {       // rows 128,129 (wave0 lanes 0..7, exec-masked)
                const int j   = 128 + (l >> 2);
                const int gpx = px0 + j - 1;
                const int kg  = (l & 3) ^ ((j >> 2) & 3);
                const void* gsrc = ((unsigned)gpx > 255u)
                    ? (const void*)zbuf
                    : (const void*)(xT + ((rowpix + gpx) * C + ic0 + kg * 8));
                gld_lds16(gsrc, (char*)Bs + 8192);
            }
            asm volatile("s_waitcnt vmcnt(0)" ::: "memory");
            __syncthreads();
            // ---- compute: 3 dx x 2 sets x 16 MFMAs ----
#pragma unroll
            for (int dxt = 0; dxt < 3; dxt++) {
                bf16x8 bfr[4];
#pragma unroll
                for (int i = 0; i < 4; i++) {
                    const int j  = wn + i * 16 + (l & 15) + dxt;   // LDS row
                    const int bq = g ^ ((j >> 2) & 3);
                    bfr[i] = *(const bf16x8*)((const char*)Bs + j * 64 + bq * 16);
                }
                bf16x8 af0[4], af1[4];
#pragma unroll
                for (int i = 0; i < 4; i++) {
                    af0[i] = *(const bf16x8*)((const char*)As[dxt][0] + a_off[i]);
                    af1[i] = *(const bf16x8*)((const char*)As[dxt][1] + a_off[i]);
                }
#pragma unroll
                for (int mi = 0; mi < 4; mi++)
#pragma unroll
                    for (int nj = 0; nj < 4; nj++) {
                        acc[0][mi][nj] = __builtin_amdgcn_mfma_f32_16x16x32_bf16(
                            af0[mi], bfr[nj], acc[0][mi][nj], 0, 0, 0);
                        acc[1][mi][nj] = __builtin_amdgcn_mfma_f32_16x16x32_bf16(
                            af1[mi], bfr[nj], acc[1][mi][nj], 0, 0, 0);
                    }
            }
        }
    }

    // ---- epilogue: NCHW bf16 stores + LDS-reduced BN partials ----
    const int colpx = px0 + wn + (l & 15);
    const int rowoc = oct * 128 + wm + (l >> 4) * 4;
#pragma unroll
    for (int s = 0; s < 2; s++) {
        unsigned short* ob = s ? out1 : out0;
#pragma unroll
        for (int mi = 0; mi < 4; mi++) {
#pragma unroll
            for (int rg = 0; rg < 4; rg++) {
                const int oc = rowoc + mi * 16 + rg;
                float ps = 0.f, pq = 0.f;
#pragma unroll
                for (int nj = 0; nj < 4; nj++) {
                    const float v = acc[s][mi][nj][rg];
                    ps += v;
                    pq = fmaf(v, v, pq);
                    const int px = colpx + nj * 16;
                    const size_t idx = ((size_t)(b * C + oc)) * HW + (size_t)r * W + px;
                    ob[idx] = f2bf(v);
                }
                // reduce over the 16 px-lanes (same oc for all l&15)
                ps += __shfl_xor(ps, 1);  pq += __shfl_xor(pq, 1);
                ps += __shfl_xor(ps, 2);  pq += __shfl_xor(pq, 2);
                ps += __shfl_xor(ps, 4);  pq += __shfl_xor(pq, 4);
                ps += __shfl_xor(ps, 8);  pq += __shfl_xor(pq, 8);
                if ((l & 15) == 0) {
                    const int loc = wm + (l >> 4) * 4 + mi * 16 + rg;  // 0..127
                    atomicAdd(&sstat[s][loc][0], ps);
                    atomicAdd(&sstat[s][loc][1], pq);
                }
            }
        }
    }
    __syncthreads();
    // one coalesced 2KB store: entry t = s*128 + loc
    stats_part[(size_t)id * 512 + t * 2 + 0] = ((float(*)[2])sstat)[t][0];
    stats_part[(size_t)id * 512 + t * 2 + 1] = ((float(*)[2])sstat)[t][1];
}

// ---------------------------------------------------------------------------
// BN reduce + finalize: sum stats_part over the 1024 matching block slots
// per (set, oc), then emit fused scale/shift.  grid = 512 (s*256 + oc).
// ---------------------------------------------------------------------------
__global__ __launch_bounds__(256) void bn_reduce_k(
    const float* __restrict__ stats_part,
    const float* __restrict__ g0, const float* __restrict__ b0,
    const float* __restrict__ g1, const float* __restrict__ b1,
    float* __restrict__ scl0, float* __restrict__ shf0,
    float* __restrict__ scl1, float* __restrict__ shf1)
{
    const int s   = blockIdx.x >> 8;
    const int gc  = blockIdx.x & 255;
    const int oct = gc >> 7;
    const int loc = gc & 127;
    const int t   = threadIdx.x;
    const int ent = (s * 128 + loc) * 2;

    float ps = 0.f, pq = 0.f;
#pragma unroll
    for (int m = 0; m < 4; m++) {
        const int id = oct + 2 * (t + 256 * m);   // ids with id&1 == oct
        ps += stats_part[(size_t)id * 512 + ent];
        pq += stats_part[(size_t)id * 512 + ent + 1];
    }
    __shared__ float rs[256], rq[256];
    rs[t] = ps; rq[t] = pq;
    __syncthreads();
    for (int o = 128; o > 0; o >>= 1) {
        if (t < o) { rs[t] += rs[t + o]; rq[t] += rq[t + o]; }
        __syncthreads();
    }
    if (t == 0) {
        const float n    = (float)Bn * HW;
        const float mean = rs[0] / n;
        const float var  = rq[0] / n - mean * mean;
        const float g    = s ? g1[gc] : g0[gc];
        const float be   = s ? b1[gc] : b0[gc];
        const float sc   = g * rsqrtf(var + 1e-5f);
        if (s) { scl1[gc] = sc; shf1[gc] = be - mean * sc; }
        else   { scl0[gc] = sc; shf0[gc] = be - mean * sc; }
    }
}

// ---------------------------------------------------------------------------
// Fused dual 1x1 GEMM (Q + K).  BK=64, single-buffer.
// Block: 256 thr = 4 waves (2x2), tile 128oc x 128px. grid = 2048 (swizzled).
// LDS 64KB -> 2 blocks/CU max.
// ---------------------------------------------------------------------------
__global__ __launch_bounds__(256, 2) void gemm2_k(
    const unsigned short* __restrict__ qin, const unsigned short* __restrict__ kin,
    const unsigned short* __restrict__ Wpq, const unsigned short* __restrict__ Wpk,
    unsigned short* __restrict__ outq, unsigned short* __restrict__ outk)
{
    __shared__ unsigned short As[2][2][128 * 32];   // [set][kc] 32KB
    __shared__ unsigned short Bs[2][2][128 * 32];   // [set][kc] 32KB

    const int id  = swz2048(blockIdx.x);
    const int oct = id & 1;
    const int ch  = (id >> 1) & 1;
    const int r   = (id >> 2) & 255;
    const int b   = id >> 10;
    const int px0 = ch * 128;

    const int t  = threadIdx.x;
    const int wv = t >> 6;
    const int l  = t & 63;
    const int wm = (wv >> 1) * 64;
    const int wn = (wv & 1) * 64;

    const int qp = (l >> 4) ^ ((l >> 2) & 3);
    int a_off[4], b_off[4];
#pragma unroll
    for (int i = 0; i < 4; i++) {
        a_off[i] = (wm + i * 16 + (l & 15)) * 64 + qp * 16;
        b_off[i] = (wn + i * 16 + (l & 15)) * 64 + qp * 16;
    }
    const int spx_base = wv * 32 + (l >> 2);
    const int skk0 = (((l & 3) ^ (l >> 4)) << 3);

    const size_t rowpix = (size_t)(b * HW) + (size_t)r * W;

    f32x4 acc[2][4][4];
#pragma unroll
    for (int s = 0; s < 2; s++)
#pragma unroll
        for (int i = 0; i < 4; i++)
#pragma unroll
            for (int j = 0; j < 4; j++) acc[s][i][j] = (f32x4){0.f, 0.f, 0.f, 0.f};

#pragma unroll 1
    for (int ip = 0; ip < 4; ++ip) {
        __syncthreads();
#pragma unroll
        for (int kc = 0; kc < 2; kc++) {
            const int icc = ip * 2 + kc;
            const size_t wofs = ((size_t)(oct * 8 + icc) * 4096) * 2 + wv * 2048 + l * 16;
            char* Aq = (char*)As[0][kc] + wv * 2048;
            char* Ak = (char*)As[1][kc] + wv * 2048;
            gld_lds16((const char*)Wpq + wofs, Aq);
            gld_lds16((const char*)Wpq + wofs + 1024, Aq + 1024);
            gld_lds16((const char*)Wpk + wofs, Ak);
            gld_lds16((const char*)Wpk + wofs + 1024, Ak + 1024);
            const int ic0 = icc * 32;
            char* Bq = (char*)Bs[0][kc] + wv * 2048;
            char* Bk = (char*)Bs[1][kc] + wv * 2048;
#pragma unroll
            for (int i = 0; i < 2; i++) {
                const int cx = px0 + spx_base + i * 16;
                gld_lds16((const void*)(qin + ((rowpix + cx) * C + ic0 + skk0)), Bq + i * 1024);
                gld_lds16((const void*)(kin + ((rowpix + cx) * C + ic0 + skk0)), Bk + i * 1024);
            }
        }
        asm volatile("s_waitcnt vmcnt(0)" ::: "memory");
        __syncthreads();
#pragma unroll
        for (int kc = 0; kc < 2; kc++) {
#pragma unroll
            for (int s = 0; s < 2; s++) {
                bf16x8 af[4], bfr[4];
#pragma unroll
                for (int i = 0; i < 4; i++) {
                    af[i]  = *(const bf16x8*)((const char*)As[s][kc] + a_off[i]);
                    bfr[i] = *(const bf16x8*)((const char*)Bs[s][kc] + b_off[i]);
                }
#pragma unroll
                for (int mi = 0; mi < 4; mi++)
#pragma unroll
                    for (int nj = 0; nj < 4; nj++)
                        acc[s][mi][nj] = __builtin_amdgcn_mfma_f32_16x16x32_bf16(
                            af[mi], bfr[nj], acc[s][mi][nj], 0, 0, 0);
            }
        }
    }

    // ---- epilogue: NHWC bf16 for both outputs ----
    const int colpx = px0 + wn + (l & 15);
    const int rowoc = oct * 128 + wm + (l >> 4) * 4;
    const size_t pxg = (size_t)(b * HW) + (size_t)r * W;
#pragma unroll
    for (int s = 0; s < 2; s++) {
        unsigned short* ob = s ? outk : outq;
#pragma unroll
        for (int mi = 0; mi < 4; mi++) {
#pragma unroll
            for (int nj = 0; nj < 4; nj++) {
                __attribute__((aligned(8))) unsigned short rv[4];
#pragma unroll
                for (int rg = 0; rg < 4; rg++) rv[rg] = f2bf(acc[s][mi][nj][rg]);
                const int oc = rowoc + mi * 16;
                const int px = colpx + nj * 16;
                *(uint2*)(ob + (pxg + px) * C + oc) = *(const uint2*)rv;
            }
        }
    }
}

// ---------------------------------------------------------------------------
// MFMA GEMM (1x1 conv, K = 256), BK=64 single-buffer (4 barrier-pairs).
// B input: NHWC bf16.  Output: NCHW fp32 / NHWC bf16.
// Block: 256 thr = 4 waves (2x2), tile 128oc x 128px. grid = 2048 (swizzled).
// ---------------------------------------------------------------------------
template<bool F32OUT, bool NHWC_OUT>
__global__ __launch_bounds__(256, 4) void gemm_k(
    const unsigned short* __restrict__ xT, const unsigned short* __restrict__ Wp,
    unsigned short* __restrict__ outb, float* __restrict__ outf)
{
    __shared__ unsigned short As[2][128 * 32];   // [kc] 16KB
    __shared__ unsigned short Bs[2][128 * 32];   // [kc] 16KB

    const int id  = swz2048(blockIdx.x);
    const int oct = id & 1;
    const int ch  = (id >> 1) & 1;
    const int r   = (id >> 2) & 255;
    const int b   = id >> 10;
    const int px0 = ch * 128;

    const int t  = threadIdx.x;
    const int wv = t >> 6;
    const int l  = t & 63;
    const int wm = (wv >> 1) * 64;
    const int wn = (wv & 1) * 64;

    const int qp = (l >> 4) ^ ((l >> 2) & 3);
    int a_off[4], b_off[4];
#pragma unroll
    for (int i = 0; i < 4; i++) {
        a_off[i] = (wm + i * 16 + (l & 15)) * 64 + qp * 16;
        b_off[i] = (wn + i * 16 + (l & 15)) * 64 + qp * 16;
    }
    const int spx_base = wv * 32 + (l >> 2);
    const int skk0 = (((l & 3) ^ (l >> 4)) << 3);

    const size_t rowpix = (size_t)(b * HW) + (size_t)r * W;

    f32x4 acc[4][4];
#pragma unroll
    for (int i = 0; i < 4; i++)
#pragma unroll
        for (int j = 0; j < 4; j++) acc[i][j] = (f32x4){0.f, 0.f, 0.f, 0.f};

#pragma unroll 1
    for (int ip = 0; ip < 4; ++ip) {
        __syncthreads();
#pragma unroll
        for (int kc = 0; kc < 2; kc++) {
            const int icc = ip * 2 + kc;
            const char* Ag = (const char*)Wp +
                ((size_t)(oct * 8 + icc) * 4096) * 2 + wv * 2048 + l * 16;
            char* AsB = (char*)As[kc] + wv * 2048;
            gld_lds16(Ag, AsB);
            gld_lds16(Ag + 1024, AsB + 1024);
            const int ic0 = icc * 32;
            char* BsB = (char*)Bs[kc] + wv * 2048;
#pragma unroll
            for (int i = 0; i < 2; i++) {
                const int cx = px0 + spx_base + i * 16;
                gld_lds16((const void*)(xT + ((rowpix + cx) * C + ic0 + skk0)), BsB + i * 1024);
            }
        }
        asm volatile("s_waitcnt vmcnt(0)" ::: "memory");
        __syncthreads();
#pragma unroll
        for (int kc = 0; kc < 2; kc++) {
            bf16x8 af[4], bfr[4];
#pragma unroll
            for (int i = 0; i < 4; i++) {
                af[i]  = *(const bf16x8*)((const char*)As[kc] + a_off[i]);
                bfr[i] = *(const bf16x8*)((const char*)Bs[kc] + b_off[i]);
            }
#pragma unroll
            for (int mi = 0; mi < 4; mi++)
#pragma unroll
                for (int nj = 0; nj < 4; nj++)
                    acc[mi][nj] = __builtin_amdgcn_mfma_f32_16x16x32_bf16(
                        af[mi], bfr[nj], acc[mi][nj], 0, 0, 0);
        }
    }

    // ---- epilogue: C/D layout col=lane&15, row=(lane>>4)*4+reg ----
    const int colpx = px0 + wn + (l & 15);
    const int rowoc = oct * 128 + wm + (l >> 4) * 4;
    if (NHWC_OUT) {
        const size_t pxg = (size_t)(b * HW) + (size_t)r * W;
#pragma unroll
        for (int mi = 0; mi < 4; mi++) {
#pragma unroll
            for (int nj = 0; nj < 4; nj++) {
                __attribute__((aligned(8))) unsigned short rv[4];
#pragma unroll
                for (int rg = 0; rg < 4; rg++) rv[rg] = f2bf(acc[mi][nj][rg]);
                const int oc = rowoc + mi * 16;
                const int px = colpx + nj * 16;
                *(uint2*)(outb + (pxg + px) * C + oc) = *(const uint2*)rv;
            }
        }
    } else {
#pragma unroll
        for (int mi = 0; mi < 4; mi++) {
#pragma unroll
            for (int nj = 0; nj < 4; nj++) {
#pragma unroll
                for (int rg = 0; rg < 4; rg++) {
                    const int oc = rowoc + mi * 16 + rg;
                    const int px = colpx + nj * 16;
                    const size_t idx = ((size_t)(b * C + oc)) * HW + (size_t)r * W + px;
                    if (F32OUT) outf[idx] = acc[mi][nj][rg];
                    else        outb[idx] = f2bf(acc[mi][nj][rg]);
                }
            }
        }
    }
}

// ---------------------------------------------------------------------------
// depthwise 3x3 with BN+relu6 fused on input read + fused per-pixel channel
// mean partials.  MERGED IEM+NEM, 32-channel blocks (27KB LDS, 5-6 blk/CU).
// In: NCHW bf16 conv raw (per set).  Out: NHWC bf16 + smean fp32 [B*HW].
// grid = 32768: c0=(id&7)*32, w0=((id>>3)&3)*64, r=(id>>5)&255,
//               b=(id>>13)&1, set=id>>14
// ---------------------------------------------------------------------------
__global__ __launch_bounds__(256) void dwconv_k(
    const unsigned short* __restrict__ a0, const unsigned short* __restrict__ a1,
    const float* __restrict__ scl0, const float* __restrict__ shf0,
    const float* __restrict__ scl1, const float* __restrict__ shf1,
    const float* __restrict__ wd0, const float* __restrict__ wd1,
    unsigned short* __restrict__ out0, unsigned short* __restrict__ out1,
    float* __restrict__ sm0, float* __restrict__ sm1)
{
    __shared__ float tile[32][3][67];   // cols w0-1 .. w0+65 -> idx 0..65
    __shared__ float wds[32 * 9];
    __shared__ float sscl[32], sshf[32];

    const int id  = blockIdx.x;
    const int c0  = (id & 7) * 32;
    const int w0  = ((id >> 3) & 3) * 64;
    const int r   = (id >> 5) & 255;
    const int b   = (id >> 13) & 1;
    const int set = id >> 14;
    const int t   = threadIdx.x;

    const unsigned short* a   = set ? a1 : a0;
    const float* scale        = set ? scl1 : scl0;
    const float* shift        = set ? shf1 : shf0;
    const float* wd           = set ? wd1 : wd0;
    unsigned short* out       = set ? out1 : out0;
    float* smean              = set ? sm1 : sm0;

    for (int i = t; i < 288; i += 256) wds[i] = wd[c0 * 9 + i];
    if (t < 32) { sscl[t] = scale[c0 + t]; sshf[t] = shift[c0 + t]; }
    __syncthreads();

    // main staging: 32c x 3row x 16seg of 4 elems (1536 items, 6 per thread)
    for (int i = t; i < 1536; i += 256) {
        const int c   = i / 48;
        const int rem = i - c * 48;
        const int row = rem >> 4, seg = rem & 15;
        const int rr  = r + row - 1;
        float f0 = 0.f, f1 = 0.f, f2 = 0.f, f3 = 0.f;
        if ((unsigned)rr < 256u) {
            const uint2 v = *(const uint2*)(a + ((size_t)(b * C + c0 + c)) * HW
                                              + (size_t)rr * W + w0 + seg * 4);
            const float sc = sscl[c], sh = sshf[c];
            f0 = fminf(fmaxf(fmaf(bflo(v.x), sc, sh), 0.f), 6.f);
            f1 = fminf(fmaxf(fmaf(bfhi(v.x), sc, sh), 0.f), 6.f);
            f2 = fminf(fmaxf(fmaf(bflo(v.y), sc, sh), 0.f), 6.f);
            f3 = fminf(fmaxf(fmaf(bfhi(v.y), sc, sh), 0.f), 6.f);
        }
        float* dst = &tile[c][row][1 + seg * 4];
        dst[0] = f0; dst[1] = f1; dst[2] = f2; dst[3] = f3;
    }
    // edges: 32c x 3row x 2side (192 items)
    for (int i = t; i < 192; i += 256) {
        const int c   = i / 6;
        const int rem = i - c * 6;
        const int row = rem >> 1, side = rem & 1;
        const int rr  = r + row - 1;
        const int col = side ? (w0 + 64) : (w0 - 1);
        float v = 0.f;
        if ((unsigned)rr < 256u && (unsigned)col < 256u) {
            float u = bf2f(a[((size_t)(b * C + c0 + c)) * HW + (size_t)rr * W + col]);
            v = fminf(fmaxf(fmaf(u, sscl[c], sshf[c]), 0.f), 6.f);
        }
        tile[c][row][side ? 65 : 0] = v;
    }
    __syncthreads();

    const int px = t >> 2, csub = t & 3;
    __attribute__((aligned(16))) unsigned short res[8];
    float psum = 0.f;
#pragma unroll
    for (int k = 0; k < 8; k++) {
        const int c = csub * 8 + k;
        const float* wp = &wds[c * 9];
        float accv = 0.f;
#pragma unroll
        for (int dy = 0; dy < 3; dy++)
#pragma unroll
            for (int dx = 0; dx < 3; dx++)
                accv = fmaf(tile[c][dy][px + dx], wp[dy * 3 + dx], accv);
        res[k] = f2bf(accv);
        psum += accv;
    }
    unsigned short* o = out + ((size_t)(b * HW) + (size_t)r * W + w0 + px) * C + c0 + csub * 8;
    *(uint4*)o = *(const uint4*)&res[0];

    // fused channel-mean partial: quad-reduce (lanes t, t^1, t^2 share px)
    psum += __shfl_xor(psum, 1);
    psum += __shfl_xor(psum, 2);
    if (csub == 0)
        atomicAdd(&smean[(size_t)(b * HW) + (size_t)r * W + w0 + px], psum * (1.f / C));
}

// ---------------------------------------------------------------------------
// windowed attention via MFMA. One wave per (b, head, wy, wx) window.
// q,k,v: NHWC bf16.  out: NHWC bf16.  setprio(1) around MFMA clusters (T5).
// ---------------------------------------------------------------------------
__global__ __launch_bounds__(64) void attn_k(
    const unsigned short* __restrict__ q, const unsigned short* __restrict__ k,
    const unsigned short* __restrict__ v, const float* __restrict__ si,
    const float* __restrict__ sn, const float* __restrict__ temp,
    unsigned short* __restrict__ out)
{
    __shared__ unsigned short Pl[64][72];   // P rows: pitch 144B (16B aligned)
    __shared__ unsigned short Vt[32][72];   // V^T rows: [d][kpix]

    const int id   = blockIdx.x;
    const int wx   = id & 31;
    const int wy   = (id >> 5) & 31;
    const int head = (id >> 10) & 7;
    const int b    = id >> 13;
    const int l    = threadIdx.x;
    const int pl15 = l & 15;
    const int g    = l >> 4;
    const int ch0  = head * 32;
    const int base = wy * 8 * W + wx * 8;       // window origin pixel
    const size_t bb = (size_t)b * HW;

    // ---- load Q/K fragments (A-frag layout: row=lane&15, kgrp=lane>>4) ----
    uint4 qv[4], kv[4];
    float qss[4], kss[4];
#pragma unroll
    for (int i = 0; i < 4; i++) {
        const int p = i * 16 + pl15;
        const size_t a = (bb + base + (p >> 3) * W + (p & 7)) * C + ch0 + g * 8;
        qv[i] = *(const uint4*)(q + a);
        kv[i] = *(const uint4*)(k + a);
        // partial squared norms over this lane's 8 channels
        float s0 = 0.f, s1 = 0.f;
        {
            uint4 u = qv[i];
            float f;
            f = bflo(u.x); s0 = fmaf(f, f, s0);  f = bfhi(u.x); s0 = fmaf(f, f, s0);
            f = bflo(u.y); s0 = fmaf(f, f, s0);  f = bfhi(u.y); s0 = fmaf(f, f, s0);
            f = bflo(u.z); s0 = fmaf(f, f, s0);  f = bfhi(u.z); s0 = fmaf(f, f, s0);
            f = bflo(u.w); s0 = fmaf(f, f, s0);  f = bfhi(u.w); s0 = fmaf(f, f, s0);
        }
        {
            uint4 u = kv[i];
            float f;
            f = bflo(u.x); s1 = fmaf(f, f, s1);  f = bfhi(u.x); s1 = fmaf(f, f, s1);
            f = bflo(u.y); s1 = fmaf(f, f, s1);  f = bfhi(u.y); s1 = fmaf(f, f, s1);
            f = bflo(u.z); s1 = fmaf(f, f, s1);  f = bfhi(u.z); s1 = fmaf(f, f, s1);
            f = bflo(u.w); s1 = fmaf(f, f, s1);  f = bfhi(u.w); s1 = fmaf(f, f, s1);
        }
        // full 32-ch norms: combine the 4 d-groups (lanes l, l^16, l^32, l^48)
        s0 += __shfl_xor(s0, 16); s0 += __shfl_xor(s0, 32);
        s1 += __shfl_xor(s1, 16); s1 += __shfl_xor(s1, 32);
        qss[i] = s0; kss[i] = s1;
    }

    // ---- stage V^T into LDS: lane l owns window pixel l (32 scalar writes) ----
    {
        const size_t a = (bb + base + (l >> 3) * W + (l & 7)) * C + ch0;
        const uint4* vp = (const uint4*)(v + a);
#pragma unroll
        for (int i = 0; i < 4; i++) {
            uint4 vv = vp[i];
            Vt[i * 8 + 0][l] = (unsigned short)(vv.x);
            Vt[i * 8 + 1][l] = (unsigned short)(vv.x >> 16);
            Vt[i * 8 + 2][l] = (unsigned short)(vv.y);
            Vt[i * 8 + 3][l] = (unsigned short)(vv.y >> 16);
            Vt[i * 8 + 4][l] = (unsigned short)(vv.z);
            Vt[i * 8 + 5][l] = (unsigned short)(vv.z >> 16);
            Vt[i * 8 + 6][l] = (unsigned short)(vv.w);
            Vt[i * 8 + 7][l] = (unsigned short)(vv.w >> 16);
        }
    }

    // ---- per-pixel scales ----
    const float tsc = temp[head] * 0.17677669529663689f;   // 32^-0.5
    float qmul[4], kscl[4];
#pragma unroll
    for (int i = 0; i < 4; i++) {
        const int p = i * 16 + pl15;
        const size_t pg = bb + base + (p >> 3) * W + (p & 7);
        const float il = si[pg];
        const float nz = sn[pg];
        qmul[i] = (1.f + il) * tsc / fmaxf(sqrtf(qss[i]), 1e-12f);
        kscl[i] = fminf(fmaxf(1.f - nz, 0.f), 1.f) / fmaxf(sqrtf(kss[i]), 1e-12f);
    }

    // ---- S = Q * K^T: 16 MFMAs ----
    f32x4 acc[4][4];
    __builtin_amdgcn_s_setprio(1);
#pragma unroll
    for (int qi = 0; qi < 4; qi++)
#pragma unroll
        for (int kj = 0; kj < 4; kj++)
            acc[qi][kj] = __builtin_amdgcn_mfma_f32_16x16x32_bf16(
                u2b(qv[qi]), u2b(kv[kj]), (f32x4){0.f, 0.f, 0.f, 0.f}, 0, 0, 0);
    __builtin_amdgcn_s_setprio(0);

    // ---- scale + softmax (rows owned: q = qi*16 + g*4 + rg) + P -> LDS ----
    float inv[4][4];
#pragma unroll
    for (int qi = 0; qi < 4; qi++) {
#pragma unroll
        for (int rg = 0; rg < 4; rg++) {
            const float qm = __shfl(qmul[qi], (g << 2) + rg);
            float s[4];
#pragma unroll
            for (int kj = 0; kj < 4; kj++) s[kj] = acc[qi][kj][rg] * kscl[kj] * qm;
            float mx = fmaxf(fmaxf(s[0], s[1]), fmaxf(s[2], s[3]));
            mx = fmaxf(mx, __shfl_xor(mx, 1));
            mx = fmaxf(mx, __shfl_xor(mx, 2));
            mx = fmaxf(mx, __shfl_xor(mx, 4));
            mx = fmaxf(mx, __shfl_xor(mx, 8));
            float sum = 0.f;
#pragma unroll
            for (int kj = 0; kj < 4; kj++) {
                const float e = __expf(s[kj] - mx);
                acc[qi][kj][rg] = e;
                sum += e;
            }
            sum += __shfl_xor(sum, 1);
            sum += __shfl_xor(sum, 2);
            sum += __shfl_xor(sum, 4);
            sum += __shfl_xor(sum, 8);
            inv[qi][rg] = 1.f / sum;
            const int qrow = qi * 16 + (g << 2) + rg;
#pragma unroll
            for (int kj = 0; kj < 4; kj++)
                Pl[qrow][pl15 + 16 * kj] = f2bf(acc[qi][kj][rg]);
        }
    }

    // ---- O = P * V: 16 MFMAs (K-dim = 64 k-pixels, 2 chunks of 32) ----
    f32x4 oacc[4][2];
#pragma unroll
    for (int qi = 0; qi < 4; qi++)
#pragma unroll
        for (int dj = 0; dj < 2; dj++) oacc[qi][dj] = (f32x4){0.f, 0.f, 0.f, 0.f};

#pragma unroll
    for (int kc = 0; kc < 2; kc++) {
        const bf16x8 vb0 = *(const bf16x8*)&Vt[pl15][kc * 32 + g * 8];
        const bf16x8 vb1 = *(const bf16x8*)&Vt[pl15 + 16][kc * 32 + g * 8];
        __builtin_amdgcn_s_setprio(1);
#pragma unroll
        for (int qi = 0; qi < 4; qi++) {
            const bf16x8 pa = *(const bf16x8*)&Pl[qi * 16 + pl15][kc * 32 + g * 8];
            oacc[qi][0] = __builtin_amdgcn_mfma_f32_16x16x32_bf16(pa, vb0, oacc[qi][0], 0, 0, 0);
            oacc[qi][1] = __builtin_amdgcn_mfma_f32_16x16x32_bf16(pa, vb1, oacc[qi][1], 0, 0, 0);
        }
        __builtin_amdgcn_s_setprio(0);
    }

    // ---- epilogue: row q = qi*16 + g*4 + rg, col d = pl15 + 16*dj ----
#pragma unroll
    for (int qi = 0; qi < 4; qi++) {
#pragma unroll
        for (int rg = 0; rg < 4; rg++) {
            const int qrow = qi * 16 + (g << 2) + rg;
            const size_t oaddr = (bb + base + (qrow >> 3) * W + (qrow & 7)) * C + ch0;
            const float sc = inv[qi][rg];
            out[oaddr + pl15]      = f2bf(oacc[qi][0][rg] * sc);
            out[oaddr + 16 + pl15] = f2bf(oacc[qi][1][rg] * sc);
        }
    }
}

// ---------------------------------------------------------------------------
extern "C" void kernel_launch(void* const* d_in, const int* in_sizes, int n_in,
                              void* d_out, int out_size, void* d_ws, size_t ws_size,
                              hipStream_t stream)
{
    const float* x        = (const float*)d_in[0];
    const float* w_iem    = (const float*)d_in[1];
    const float* g_iem    = (const float*)d_in[2];
    const float* b_iem    = (const float*)d_in[3];
    const float* w_nem    = (const float*)d_in[4];
    const float* g_nem    = (const float*)d_in[5];
    const float* b_nem    = (const float*)d_in[6];
    const float* w_iem_dw = (const float*)d_in[7];
    const float* w_nem_dw = (const float*)d_in[8];
    const float* w_q      = (const float*)d_in[9];
    const float* w_k      = (const float*)d_in[10];
    const float* w_v      = (const float*)d_in[11];
    const float* w_proj   = (const float*)d_in[12];
    const float* temp     = (const float*)d_in[13];

    // workspace carve-up (bytes)
    char* p = (char*)d_ws;
    unsigned short* zbuf = (unsigned short*)p;      p += 256;
    float* scl0 = (float*)p;                        p += 256 * 4;
    float* shf0 = (float*)p;                        p += 256 * 4;
    float* scl1 = (float*)p;                        p += 256 * 4;
    float* shf1 = (float*)p;                        p += 256 * 4;
    float* stats_part = (float*)p;                  p += (size_t)2048 * 512 * 4;  // 4MB
    float* sI  = (float*)p;                         p += (size_t)Bn * HW * 4;
    float* sN  = (float*)p;                         p += (size_t)Bn * HW * 4;
    unsigned short* Wp_iem = (unsigned short*)p;    p += 589824 * 2;
    unsigned short* Wp_nem = (unsigned short*)p;    p += 589824 * 2;
    unsigned short* Wpq = (unsigned short*)p;       p += 65536 * 2;
    unsigned short* Wpk = (unsigned short*)p;       p += 65536 * 2;
    unsigned short* Wpv = (unsigned short*)p;       p += 65536 * 2;
    unsigned short* Wpp = (unsigned short*)p;       p += 65536 * 2;
    unsigned short* xT   = (unsigned short*)p;      p += Bn * CHW * 2;  // NHWC bf16
    unsigned short* bufA = (unsigned short*)p;      p += Bn * CHW * 2;  // IEM raw (NCHW) / Q (NHWC)
    unsigned short* Ibf  = (unsigned short*)p;      p += Bn * CHW * 2;  // illum NHWC / attn out NHWC
    unsigned short* Nbf  = (unsigned short*)p;      p += Bn * CHW * 2;  // noise NHWC / V (NHWC)
    unsigned short* Obf  = (unsigned short*)p;      p += Bn * CHW * 2;  // NEM raw (NCHW) / K (NHWC)

    hipMemsetAsync(zbuf, 0, 256, stream);
    hipMemsetAsync(sI, 0, (size_t)Bn * HW * 4 * 2, stream);   // sI + sN contiguous

    packx_k<<<8192, 256, 0, stream>>>(x, xT);
    pack_k<<<2304, 256, 0, stream>>>(w_iem, Wp_iem, 9);
    pack_k<<<2304, 256, 0, stream>>>(w_nem, Wp_nem, 9);
    pack4_k<<<1024, 256, 0, stream>>>(w_q, w_k, w_v, w_proj, Wpq, Wpk, Wpv, Wpp);

    // fused IEM+NEM 3x3 conv (halo-shared B) + contention-free BN partials
    conv2_k<<<2048, 256, 0, stream>>>(xT, Wp_iem, Wp_nem, bufA, Obf, zbuf, stats_part);
    bn_reduce_k<<<512, 256, 0, stream>>>(stats_part, g_iem, b_iem, g_nem, b_nem,
                                         scl0, shf0, scl1, shf1);

    // merged depthwise (both sets; BN+relu6 on read, channel-mean on write)
    dwconv_k<<<32768, 256, 0, stream>>>(bufA, Obf, scl0, shf0, scl1, shf1,
                                        w_iem_dw, w_nem_dw, Ibf, Nbf, sI, sN);

    // fused Q+K projections -> NHWC bf16 (Q->bufA, K->Obf)
    gemm2_k<<<2048, 256, 0, stream>>>(Ibf, Nbf, Wpq, Wpk, bufA, Obf);
    // V projection (Nbf consumed by gemm2 above)
    gemm_k<false, true><<<2048, 256, 0, stream>>>(xT, Wpv, Nbf, nullptr);

    attn_k<<<16384, 64, 0, stream>>>(bufA, Obf, Nbf, sI, sN, temp, Ibf);

    // final projection -> fp32 d_out (NCHW)
    gemm_k<true, false><<<2048, 256, 0, stream>>>(Ibf, Wpp, nullptr, (float*)d_out);
}

// Round 13
// 945.146 us; speedup vs baseline: 1.1326x; 1.0503x over previous
//
#include <hip/hip_runtime.h>
#include <math.h>

// ---------------------------------------------------------------------------
// Problem constants
constexpr int Bn  = 2;
constexpr int C   = 256;
constexpr int H   = 256;
constexpr int W   = 256;
constexpr int HW  = H * W;          // 65536
constexpr size_t CHW = (size_t)C * HW;

typedef __bf16 bf16x8 __attribute__((ext_vector_type(8)));
typedef float  f32x4  __attribute__((ext_vector_type(4)));

// fp32 -> bf16 round-to-nearest-even
__device__ __forceinline__ unsigned short f2bf(float f) {
    unsigned int u = __float_as_uint(f);
    u += 0x7fffu + ((u >> 16) & 1u);
    return (unsigned short)(u >> 16);
}
__device__ __forceinline__ float bf2f(unsigned short h) {
    return __uint_as_float(((unsigned int)h) << 16);
}
// two bf16 packed in a uint -> floats (hi needs only a mask)
__device__ __forceinline__ float bflo(unsigned int u) { return __uint_as_float(u << 16); }
__device__ __forceinline__ float bfhi(unsigned int u) { return __uint_as_float(u & 0xffff0000u); }

__device__ __forceinline__ bf16x8 u2b(uint4 u) {
    union { uint4 a; bf16x8 b; } c; c.a = u; return c.b;
}

// async global->LDS, 16B per lane; LDS dest = uniform base + lane*16
__device__ __forceinline__ void gld_lds16(const void* g, void* lds) {
    __builtin_amdgcn_global_load_lds(
        (const __attribute__((address_space(1))) unsigned int*)g,
        (__attribute__((address_space(3))) unsigned int*)lds, 16, 0, 0);
}

// XCD-aware bijective swizzle for 2048-block grids (2048 % 8 == 0)
__device__ __forceinline__ int swz2048(int bid) {
    return ((bid & 7) << 8) | (bid >> 3);
}

// ---------------------------------------------------------------------------
// packx: x fp32 NCHW -> bf16 NHWC.  Tile 64c x 64px via LDS transpose.
// grid = (2*65536/64) * 4 = 8192 blocks
// ---------------------------------------------------------------------------
__global__ __launch_bounds__(256) void packx_k(
    const float* __restrict__ x, unsigned short* __restrict__ xT)
{
    __shared__ float tl[64][65];
    const int id = blockIdx.x;
    const int ct = id & 3;
    const size_t px0 = (size_t)(id >> 2) * 64;   // global pixel (incl batch)
    const int b  = (int)(px0 >> 16);
    const int hw = (int)(px0 & 65535);
    const int c0 = ct * 64;
    const int t  = threadIdx.x;

    {   // load: thread (cl, pseg): 16 px of channel cl
        const int cl = t >> 2, pseg = t & 3;
        const float* src = x + ((size_t)(b * C + c0 + cl)) * HW + hw + pseg * 16;
#pragma unroll
        for (int i = 0; i < 4; i++) {
            float4 v = *(const float4*)(src + i * 4);
            tl[cl][pseg * 16 + i * 4 + 0] = v.x;
            tl[cl][pseg * 16 + i * 4 + 1] = v.y;
            tl[cl][pseg * 16 + i * 4 + 2] = v.z;
            tl[cl][pseg * 16 + i * 4 + 3] = v.w;
        }
    }
    __syncthreads();
    {   // store: thread (pl, csec): 16 channels of pixel pl, contiguous in NHWC
        const int pl = t >> 2, csec = t & 3;
        __attribute__((aligned(16))) unsigned short rv[16];
#pragma unroll
        for (int j = 0; j < 16; j++) rv[j] = f2bf(tl[csec * 16 + j][pl]);
        unsigned short* dst = xT + (px0 + pl) * C + c0 + csec * 16;
        *(uint4*)dst       = *(const uint4*)&rv[0];
        *(uint4*)(dst + 8) = *(const uint4*)&rv[8];
    }
}

// ---------------------------------------------------------------------------
// pack weights into the LDS image the GEMM stages:
// layout [taps][oct(2)][icc(8)][ocl(128)][kslot(32)], with XOR-4 swizzle
// ---------------------------------------------------------------------------
__global__ __launch_bounds__(256) void pack_k(
    const float* __restrict__ w, unsigned short* __restrict__ out, int taps)
{
    const int e = blockIdx.x * 256 + threadIdx.x;
    const int kslot = e & 31;
    const int ocl   = (e >> 5) & 127;
    const int icc   = (e >> 12) & 7;
    const int oct   = (e >> 15) & 1;
    const int off   = e >> 16;
    const int oc = oct * 128 + ocl;
    const int q  = kslot >> 3, j = kslot & 7;
    const int ic = icc * 32 + ((q ^ ((ocl >> 2) & 3)) << 3) + j;
    out[e] = f2bf(w[((size_t)oc * C + ic) * taps + off]);
}

// ---------------------------------------------------------------------------
// pack the four 1x1 weight matrices in ONE launch.  grid = 1024
// ---------------------------------------------------------------------------
__global__ __launch_bounds__(256) void pack4_k(
    const float* __restrict__ wq, const float* __restrict__ wk,
    const float* __restrict__ wv, const float* __restrict__ wp,
    unsigned short* __restrict__ oq, unsigned short* __restrict__ ok,
    unsigned short* __restrict__ ov, unsigned short* __restrict__ op)
{
    const int bid  = blockIdx.x;
    const int wsel = bid >> 8;
    const int e    = (bid & 255) * 256 + threadIdx.x;
    const float* w = (wsel == 0) ? wq : (wsel == 1) ? wk : (wsel == 2) ? wv : wp;
    unsigned short* out = (wsel == 0) ? oq : (wsel == 1) ? ok : (wsel == 2) ? ov : op;
    const int kslot = e & 31;
    const int ocl   = (e >> 5) & 127;
    const int icc   = (e >> 12) & 7;
    const int oct   = (e >> 15) & 1;
    const int oc = oct * 128 + ocl;
    const int q  = kslot >> 3, j = kslot & 7;
    const int ic = icc * 32 + ((q ^ ((ocl >> 2) & 3)) << 3) + j;
    out[e] = f2bf(w[(size_t)oc * C + ic]);
}

// ---------------------------------------------------------------------------
// Fused dual 3x3 conv (IEM + NEM) with HALO-SHARED B staging.
// Output now NHWC bf16 (uint2 stores like gemm2; dwconv reads NHWC).
// BN sum/sumsq fused contention-free (LDS reduce + per-block slot store).
// Block: 256 thr = 4 waves (2x2), tile 128oc x 128px. grid = 2048 (swizzled).
// launch_bounds(256,2): measured optimum ((256,3) spills, r10).
// ---------------------------------------------------------------------------
__global__ __launch_bounds__(256, 2) void conv2_k(
    const unsigned short* __restrict__ xT,
    const unsigned short* __restrict__ Wp0, const unsigned short* __restrict__ Wp1,
    unsigned short* __restrict__ out0, unsigned short* __restrict__ out1,
    const unsigned short* __restrict__ zbuf, float* __restrict__ stats_part)
{
    __shared__ unsigned short As[3][2][128 * 32];   // [dxt][set]  48KB
    __shared__ unsigned short Bs[136 * 32];         // halo rows 0..129  8.5KB
    __shared__ float sstat[2][128][2];              // [set][loc][sum|ssq] 2KB

    const int id  = swz2048(blockIdx.x);
    const int oct = id & 1;
    const int ch  = (id >> 1) & 1;
    const int r   = (id >> 2) & 255;
    const int b   = id >> 10;
    const int px0 = ch * 128;

    const int t  = threadIdx.x;
    const int wv = t >> 6;
    const int l  = t & 63;
    const int wm = (wv >> 1) * 64;
    const int wn = (wv & 1) * 64;
    const int g  = l >> 4;

    // zero stats LDS (first K-loop barrier orders this before epilogue use)
    ((float*)sstat)[t]       = 0.f;
    ((float*)sstat)[t + 256] = 0.f;

    // A frag read offsets (swizzled quad, same as pack layout)
    const int qp = (l >> 4) ^ ((l >> 2) & 3);
    int a_off[4];
#pragma unroll
    for (int i = 0; i < 4; i++)
        a_off[i] = (wm + i * 16 + (l & 15)) * 64 + qp * 16;   // bytes

    // valid conv rows (block-uniform contiguous range of dy)
    const int dy_lo = (r == 0) ? 1 : 0;
    const int dy_hi = (r == 255) ? 1 : 2;

    f32x4 acc[2][4][4];
#pragma unroll
    for (int s = 0; s < 2; s++)
#pragma unroll
        for (int i = 0; i < 4; i++)
#pragma unroll
            for (int j = 0; j < 4; j++) acc[s][i][j] = (f32x4){0.f, 0.f, 0.f, 0.f};

#pragma unroll 1
    for (int dy = dy_lo; dy <= dy_hi; ++dy) {
        const int rr = r + dy - 1;            // in [0,255] by construction
        const size_t rowpix = (size_t)(b * HW) + (size_t)rr * W;
#pragma unroll 1
        for (int icc = 0; icc < 8; ++icc) {
            __syncthreads();   // previous chunk's frag reads done
            // ---- stage A: 3 dx-taps x 2 sets (8KB tiles) ----
#pragma unroll
            for (int dxt = 0; dxt < 3; dxt++) {
                const int off = dy * 3 + dxt;
                const size_t wofs = ((size_t)(((off * 2 + oct) * 8 + icc)) * 4096) * 2
                                    + wv * 2048 + l * 16;
                char* A0 = (char*)As[dxt][0] + wv * 2048;
                char* A1 = (char*)As[dxt][1] + wv * 2048;
                gld_lds16((const char*)Wp0 + wofs, A0);
                gld_lds16((const char*)Wp0 + wofs + 1024, A0 + 1024);
                gld_lds16((const char*)Wp1 + wofs, A1);
                gld_lds16((const char*)Wp1 + wofs + 1024, A1 + 1024);
            }
            // ---- stage B once, with halo (rows j=0..129, gpx = px0+j-1) ----
            const int ic0 = icc * 32;
#pragma unroll
            for (int i = 0; i < 2; i++) {
                const int j   = wv * 16 + (l >> 2) + i * 64;    // 0..127
                const int gpx = px0 + j - 1;
                const int kg  = (l & 3) ^ ((j >> 2) & 3);
                const void* gsrc = ((unsigned)gpx > 255u)
                    ? (const void*)zbuf
                    : (const void*)(xT + ((rowpix + gpx) * C + ic0 + kg * 8));
                gld_lds16(gsrc, (char*)Bs + wv * 1024 + i * 4096);
            }
            if (t < 8) {       // rows 128,129 (wave0 lanes 0..7, exec-masked)
                const int j   = 128 + (l >> 2);
                const int gpx = px0 + j - 1;
                const int kg  = (l & 3) ^ ((j >> 2) & 3);
                const void* gsrc = ((unsigned)gpx > 255u)
                    ? (const void*)zbuf
                    : (const void*)(xT + ((rowpix + gpx) * C + ic0 + kg * 8));
                gld_lds16(gsrc, (char*)Bs + 8192);
            }
            asm volatile("s_waitcnt vmcnt(0)" ::: "memory");
            __syncthreads();
            // ---- compute: 3 dx x 2 sets x 16 MFMAs ----
#pragma unroll
            for (int dxt = 0; dxt < 3; dxt++) {
                bf16x8 bfr[4];
#pragma unroll
                for (int i = 0; i < 4; i++) {
                    const int j  = wn + i * 16 + (l & 15) + dxt;   // LDS row
                    const int bq = g ^ ((j >> 2) & 3);
                    bfr[i] = *(const bf16x8*)((const char*)Bs + j * 64 + bq * 16);
                }
                bf16x8 af0[4], af1[4];
#pragma unroll
                for (int i = 0; i < 4; i++) {
                    af0[i] = *(const bf16x8*)((const char*)As[dxt][0] + a_off[i]);
                    af1[i] = *(const bf16x8*)((const char*)As[dxt][1] + a_off[i]);
                }
#pragma unroll
                for (int mi = 0; mi < 4; mi++)
#pragma unroll
                    for (int nj = 0; nj < 4; nj++) {
                        acc[0][mi][nj] = __builtin_amdgcn_mfma_f32_16x16x32_bf16(
                            af0[mi], bfr[nj], acc[0][mi][nj], 0, 0, 0);
                        acc[1][mi][nj] = __builtin_amdgcn_mfma_f32_16x16x32_bf16(
                            af1[mi], bfr[nj], acc[1][mi][nj], 0, 0, 0);
                    }
            }
        }
    }

    // ---- epilogue: NHWC bf16 stores (uint2, 4 consecutive oc) + BN partials ----
    const int colpx = px0 + wn + (l & 15);
    const int rowoc = oct * 128 + wm + (l >> 4) * 4;
    const size_t pxg = (size_t)(b * HW) + (size_t)r * W;
#pragma unroll
    for (int s = 0; s < 2; s++) {
        unsigned short* ob = s ? out1 : out0;
#pragma unroll
        for (int mi = 0; mi < 4; mi++) {
#pragma unroll
            for (int nj = 0; nj < 4; nj++) {
                __attribute__((aligned(8))) unsigned short rv[4];
#pragma unroll
                for (int rg = 0; rg < 4; rg++) rv[rg] = f2bf(acc[s][mi][nj][rg]);
                const int oc = rowoc + mi * 16;
                const int px = colpx + nj * 16;
                *(uint2*)(ob + (pxg + px) * C + oc) = *(const uint2*)rv;
            }
#pragma unroll
            for (int rg = 0; rg < 4; rg++) {
                float ps = 0.f, pq = 0.f;
#pragma unroll
                for (int nj = 0; nj < 4; nj++) {
                    const float v = acc[s][mi][nj][rg];
                    ps += v;
                    pq = fmaf(v, v, pq);
                }
                // reduce over the 16 px-lanes (same oc for all l&15)
                ps += __shfl_xor(ps, 1);  pq += __shfl_xor(pq, 1);
                ps += __shfl_xor(ps, 2);  pq += __shfl_xor(pq, 2);
                ps += __shfl_xor(ps, 4);  pq += __shfl_xor(pq, 4);
                ps += __shfl_xor(ps, 8);  pq += __shfl_xor(pq, 8);
                if ((l & 15) == 0) {
                    const int loc = wm + (l >> 4) * 4 + mi * 16 + rg;  // 0..127
                    atomicAdd(&sstat[s][loc][0], ps);
                    atomicAdd(&sstat[s][loc][1], pq);
                }
            }
        }
    }
    __syncthreads();
    // one coalesced 2KB store: entry t = s*128 + loc
    stats_part[(size_t)id * 512 + t * 2 + 0] = ((float(*)[2])sstat)[t][0];
    stats_part[(size_t)id * 512 + t * 2 + 1] = ((float(*)[2])sstat)[t][1];
}

// ---------------------------------------------------------------------------
// BN reduce + finalize: sum stats_part over the 1024 matching block slots
// per (set, oc), then emit fused scale/shift.  grid = 512 (s*256 + oc).
// ---------------------------------------------------------------------------
__global__ __launch_bounds__(256) void bn_reduce_k(
    const float* __restrict__ stats_part,
    const float* __restrict__ g0, const float* __restrict__ b0,
    const float* __restrict__ g1, const float* __restrict__ b1,
    float* __restrict__ scl0, float* __restrict__ shf0,
    float* __restrict__ scl1, float* __restrict__ shf1)
{
    const int s   = blockIdx.x >> 8;
    const int gc  = blockIdx.x & 255;
    const int oct = gc >> 7;
    const int loc = gc & 127;
    const int t   = threadIdx.x;
    const int ent = (s * 128 + loc) * 2;

    float ps = 0.f, pq = 0.f;
#pragma unroll
    for (int m = 0; m < 4; m++) {
        const int id = oct + 2 * (t + 256 * m);   // ids with id&1 == oct
        ps += stats_part[(size_t)id * 512 + ent];
        pq += stats_part[(size_t)id * 512 + ent + 1];
    }
    __shared__ float rs[256], rq[256];
    rs[t] = ps; rq[t] = pq;
    __syncthreads();
    for (int o = 128; o > 0; o >>= 1) {
        if (t < o) { rs[t] += rs[t + o]; rq[t] += rq[t + o]; }
        __syncthreads();
    }
    if (t == 0) {
        const float n    = (float)Bn * HW;
        const float mean = rs[0] / n;
        const float var  = rq[0] / n - mean * mean;
        const float g    = s ? g1[gc] : g0[gc];
        const float be   = s ? b1[gc] : b0[gc];
        const float sc   = g * rsqrtf(var + 1e-5f);
        if (s) { scl1[gc] = sc; shf1[gc] = be - mean * sc; }
        else   { scl0[gc] = sc; shf0[gc] = be - mean * sc; }
    }
}

// ---------------------------------------------------------------------------
// Fused dual 1x1 GEMM (Q + K).  BK=64, single-buffer.
// Block: 256 thr = 4 waves (2x2), tile 128oc x 128px. grid = 2048 (swizzled).
// LDS 64KB -> 2 blocks/CU max.
// ---------------------------------------------------------------------------
__global__ __launch_bounds__(256, 2) void gemm2_k(
    const unsigned short* __restrict__ qin, const unsigned short* __restrict__ kin,
    const unsigned short* __restrict__ Wpq, const unsigned short* __restrict__ Wpk,
    unsigned short* __restrict__ outq, unsigned short* __restrict__ outk)
{
    __shared__ unsigned short As[2][2][128 * 32];   // [set][kc] 32KB
    __shared__ unsigned short Bs[2][2][128 * 32];   // [set][kc] 32KB

    const int id  = swz2048(blockIdx.x);
    const int oct = id & 1;
    const int ch  = (id >> 1) & 1;
    const int r   = (id >> 2) & 255;
    const int b   = id >> 10;
    const int px0 = ch * 128;

    const int t  = threadIdx.x;
    const int wv = t >> 6;
    const int l  = t & 63;
    const int wm = (wv >> 1) * 64;
    const int wn = (wv & 1) * 64;

    const int qp = (l >> 4) ^ ((l >> 2) & 3);
    int a_off[4], b_off[4];
#pragma unroll
    for (int i = 0; i < 4; i++) {
        a_off[i] = (wm + i * 16 + (l & 15)) * 64 + qp * 16;
        b_off[i] = (wn + i * 16 + (l & 15)) * 64 + qp * 16;
    }
    const int spx_base = wv * 32 + (l >> 2);
    const int skk0 = (((l & 3) ^ (l >> 4)) << 3);

    const size_t rowpix = (size_t)(b * HW) + (size_t)r * W;

    f32x4 acc[2][4][4];
#pragma unroll
    for (int s = 0; s < 2; s++)
#pragma unroll
        for (int i = 0; i < 4; i++)
#pragma unroll
            for (int j = 0; j < 4; j++) acc[s][i][j] = (f32x4){0.f, 0.f, 0.f, 0.f};

#pragma unroll 1
    for (int ip = 0; ip < 4; ++ip) {
        __syncthreads();
#pragma unroll
        for (int kc = 0; kc < 2; kc++) {
            const int icc = ip * 2 + kc;
            const size_t wofs = ((size_t)(oct * 8 + icc) * 4096) * 2 + wv * 2048 + l * 16;
            char* Aq = (char*)As[0][kc] + wv * 2048;
            char* Ak = (char*)As[1][kc] + wv * 2048;
            gld_lds16((const char*)Wpq + wofs, Aq);
            gld_lds16((const char*)Wpq + wofs + 1024, Aq + 1024);
            gld_lds16((const char*)Wpk + wofs, Ak);
            gld_lds16((const char*)Wpk + wofs + 1024, Ak + 1024);
            const int ic0 = icc * 32;
            char* Bq = (char*)Bs[0][kc] + wv * 2048;
            char* Bk = (char*)Bs[1][kc] + wv * 2048;
#pragma unroll
            for (int i = 0; i < 2; i++) {
                const int cx = px0 + spx_base + i * 16;
                gld_lds16((const void*)(qin + ((rowpix + cx) * C + ic0 + skk0)), Bq + i * 1024);
                gld_lds16((const void*)(kin + ((rowpix + cx) * C + ic0 + skk0)), Bk + i * 1024);
            }
        }
        asm volatile("s_waitcnt vmcnt(0)" ::: "memory");
        __syncthreads();
#pragma unroll
        for (int kc = 0; kc < 2; kc++) {
#pragma unroll
            for (int s = 0; s < 2; s++) {
                bf16x8 af[4], bfr[4];
#pragma unroll
                for (int i = 0; i < 4; i++) {
                    af[i]  = *(const bf16x8*)((const char*)As[s][kc] + a_off[i]);
                    bfr[i] = *(const bf16x8*)((const char*)Bs[s][kc] + b_off[i]);
                }
#pragma unroll
                for (int mi = 0; mi < 4; mi++)
#pragma unroll
                    for (int nj = 0; nj < 4; nj++)
                        acc[s][mi][nj] = __builtin_amdgcn_mfma_f32_16x16x32_bf16(
                            af[mi], bfr[nj], acc[s][mi][nj], 0, 0, 0);
            }
        }
    }

    // ---- epilogue: NHWC bf16 for both outputs ----
    const int colpx = px0 + wn + (l & 15);
    const int rowoc = oct * 128 + wm + (l >> 4) * 4;
    const size_t pxg = (size_t)(b * HW) + (size_t)r * W;
#pragma unroll
    for (int s = 0; s < 2; s++) {
        unsigned short* ob = s ? outk : outq;
#pragma unroll
        for (int mi = 0; mi < 4; mi++) {
#pragma unroll
            for (int nj = 0; nj < 4; nj++) {
                __attribute__((aligned(8))) unsigned short rv[4];
#pragma unroll
                for (int rg = 0; rg < 4; rg++) rv[rg] = f2bf(acc[s][mi][nj][rg]);
                const int oc = rowoc + mi * 16;
                const int px = colpx + nj * 16;
                *(uint2*)(ob + (pxg + px) * C + oc) = *(const uint2*)rv;
            }
        }
    }
}

// ---------------------------------------------------------------------------
// MFMA GEMM (1x1 conv, K = 256), BK=64 single-buffer (4 barrier-pairs).
// B input: NHWC bf16.  Output: NCHW fp32 / NHWC bf16.
// Block: 256 thr = 4 waves (2x2), tile 128oc x 128px. grid = 2048 (swizzled).
// ---------------------------------------------------------------------------
template<bool F32OUT, bool NHWC_OUT>
__global__ __launch_bounds__(256, 4) void gemm_k(
    const unsigned short* __restrict__ xT, const unsigned short* __restrict__ Wp,
    unsigned short* __restrict__ outb, float* __restrict__ outf)
{
    __shared__ unsigned short As[2][128 * 32];   // [kc] 16KB
    __shared__ unsigned short Bs[2][128 * 32];   // [kc] 16KB

    const int id  = swz2048(blockIdx.x);
    const int oct = id & 1;
    const int ch  = (id >> 1) & 1;
    const int r   = (id >> 2) & 255;
    const int b   = id >> 10;
    const int px0 = ch * 128;

    const int t  = threadIdx.x;
    const int wv = t >> 6;
    const int l  = t & 63;
    const int wm = (wv >> 1) * 64;
    const int wn = (wv & 1) * 64;

    const int qp = (l >> 4) ^ ((l >> 2) & 3);
    int a_off[4], b_off[4];
#pragma unroll
    for (int i = 0; i < 4; i++) {
        a_off[i] = (wm + i * 16 + (l & 15)) * 64 + qp * 16;
        b_off[i] = (wn + i * 16 + (l & 15)) * 64 + qp * 16;
    }
    const int spx_base = wv * 32 + (l >> 2);
    const int skk0 = (((l & 3) ^ (l >> 4)) << 3);

    const size_t rowpix = (size_t)(b * HW) + (size_t)r * W;

    f32x4 acc[4][4];
#pragma unroll
    for (int i = 0; i < 4; i++)
#pragma unroll
        for (int j = 0; j < 4; j++) acc[i][j] = (f32x4){0.f, 0.f, 0.f, 0.f};

#pragma unroll 1
    for (int ip = 0; ip < 4; ++ip) {
        __syncthreads();
#pragma unroll
        for (int kc = 0; kc < 2; kc++) {
            const int icc = ip * 2 + kc;
            const char* Ag = (const char*)Wp +
                ((size_t)(oct * 8 + icc) * 4096) * 2 + wv * 2048 + l * 16;
            char* AsB = (char*)As[kc] + wv * 2048;
            gld_lds16(Ag, AsB);
            gld_lds16(Ag + 1024, AsB + 1024);
            const int ic0 = icc * 32;
            char* BsB = (char*)Bs[kc] + wv * 2048;
#pragma unroll
            for (int i = 0; i < 2; i++) {
                const int cx = px0 + spx_base + i * 16;
                gld_lds16((const void*)(xT + ((rowpix + cx) * C + ic0 + skk0)), BsB + i * 1024);
            }
        }
        asm volatile("s_waitcnt vmcnt(0)" ::: "memory");
        __syncthreads();
#pragma unroll
        for (int kc = 0; kc < 2; kc++) {
            bf16x8 af[4], bfr[4];
#pragma unroll
            for (int i = 0; i < 4; i++) {
                af[i]  = *(const bf16x8*)((const char*)As[kc] + a_off[i]);
                bfr[i] = *(const bf16x8*)((const char*)Bs[kc] + b_off[i]);
            }
#pragma unroll
            for (int mi = 0; mi < 4; mi++)
#pragma unroll
                for (int nj = 0; nj < 4; nj++)
                    acc[mi][nj] = __builtin_amdgcn_mfma_f32_16x16x32_bf16(
                        af[mi], bfr[nj], acc[mi][nj], 0, 0, 0);
        }
    }

    // ---- epilogue: C/D layout col=lane&15, row=(lane>>4)*4+reg ----
    const int colpx = px0 + wn + (l & 15);
    const int rowoc = oct * 128 + wm + (l >> 4) * 4;
    if (NHWC_OUT) {
        const size_t pxg = (size_t)(b * HW) + (size_t)r * W;
#pragma unroll
        for (int mi = 0; mi < 4; mi++) {
#pragma unroll
            for (int nj = 0; nj < 4; nj++) {
                __attribute__((aligned(8))) unsigned short rv[4];
#pragma unroll
                for (int rg = 0; rg < 4; rg++) rv[rg] = f2bf(acc[mi][nj][rg]);
                const int oc = rowoc + mi * 16;
                const int px = colpx + nj * 16;
                *(uint2*)(outb + (pxg + px) * C + oc) = *(const uint2*)rv;
            }
        }
    } else {
#pragma unroll
        for (int mi = 0; mi < 4; mi++) {
#pragma unroll
            for (int nj = 0; nj < 4; nj++) {
#pragma unroll
                for (int rg = 0; rg < 4; rg++) {
                    const int oc = rowoc + mi * 16 + rg;
                    const int px = colpx + nj * 16;
                    const size_t idx = ((size_t)(b * C + oc)) * HW + (size_t)r * W + px;
                    if (F32OUT) outf[idx] = acc[mi][nj][rg];
                    else        outb[idx] = f2bf(acc[mi][nj][rg]);
                }
            }
        }
    }
}

// ---------------------------------------------------------------------------
// depthwise 3x3 with BN+relu6 fused on input read + fused per-pixel channel
// mean partials.  MERGED IEM+NEM, 32-channel blocks (27KB LDS, 5-6 blk/CU).
// In: NHWC bf16 conv raw (16B uint4 loads, 64B contiguous per pixel).
// Out: NHWC bf16 + smean fp32 [B*HW].
// grid = 32768: c0=(id&7)*32, w0=((id>>3)&3)*64, r=(id>>5)&255,
//               b=(id>>13)&1, set=id>>14
// ---------------------------------------------------------------------------
__global__ __launch_bounds__(256) void dwconv_k(
    const unsigned short* __restrict__ a0, const unsigned short* __restrict__ a1,
    const float* __restrict__ scl0, const float* __restrict__ shf0,
    const float* __restrict__ scl1, const float* __restrict__ shf1,
    const float* __restrict__ wd0, const float* __restrict__ wd1,
    unsigned short* __restrict__ out0, unsigned short* __restrict__ out1,
    float* __restrict__ sm0, float* __restrict__ sm1)
{
    __shared__ float tile[32][3][67];   // [c][row][col], col = gpx - (w0-1), 0..65
    __shared__ float wds[32 * 9];
    __shared__ float sscl[32], sshf[32];

    const int id  = blockIdx.x;
    const int c0  = (id & 7) * 32;
    const int w0  = ((id >> 3) & 3) * 64;
    const int r   = (id >> 5) & 255;
    const int b   = (id >> 13) & 1;
    const int set = id >> 14;
    const int t   = threadIdx.x;

    const unsigned short* a   = set ? a1 : a0;
    const float* scale        = set ? scl1 : scl0;
    const float* shift        = set ? shf1 : shf0;
    const float* wd           = set ? wd1 : wd0;
    unsigned short* out       = set ? out1 : out0;
    float* smean              = set ? sm1 : sm0;

    for (int i = t; i < 288; i += 256) wds[i] = wd[c0 * 9 + i];
    if (t < 32) { sscl[t] = scale[c0 + t]; sshf[t] = shift[c0 + t]; }
    __syncthreads();

    // staging from NHWC: 3 rows x 66 px x 4 chunks of 8 ch = 792 uint4 loads
    for (int i = t; i < 792; i += 256) {
        const int row = i / 264;
        const int rem = i - row * 264;
        const int pxc = rem >> 2;          // 0..65  (col in tile)
        const int ck  = rem & 3;           // channel chunk (8 ch)
        const int rr  = r + row - 1;
        const int gpx = w0 - 1 + pxc;
        const int cb  = ck * 8;
        float f[8];
#pragma unroll
        for (int j = 0; j < 8; j++) f[j] = 0.f;
        if ((unsigned)rr < 256u && (unsigned)gpx < 256u) {
            const uint4 v = *(const uint4*)(a +
                ((size_t)(b * HW) + (size_t)rr * W + gpx) * C + c0 + cb);
            f[0] = bflo(v.x); f[1] = bfhi(v.x);
            f[2] = bflo(v.y); f[3] = bfhi(v.y);
            f[4] = bflo(v.z); f[5] = bfhi(v.z);
            f[6] = bflo(v.w); f[7] = bfhi(v.w);
#pragma unroll
            for (int j = 0; j < 8; j++)
                f[j] = fminf(fmaxf(fmaf(f[j], sscl[cb + j], sshf[cb + j]), 0.f), 6.f);
        }
#pragma unroll
        for (int j = 0; j < 8; j++) tile[cb + j][row][pxc] = f[j];
    }
    __syncthreads();

    const int px = t >> 2, csub = t & 3;
    __attribute__((aligned(16))) unsigned short res[8];
    float psum = 0.f;
#pragma unroll
    for (int k = 0; k < 8; k++) {
        const int c = csub * 8 + k;
        const float* wp = &wds[c * 9];
        float accv = 0.f;
#pragma unroll
        for (int dy = 0; dy < 3; dy++)
#pragma unroll
            for (int dx = 0; dx < 3; dx++)
                accv = fmaf(tile[c][dy][px + dx], wp[dy * 3 + dx], accv);
        res[k] = f2bf(accv);
        psum += accv;
    }
    unsigned short* o = out + ((size_t)(b * HW) + (size_t)r * W + w0 + px) * C + c0 + csub * 8;
    *(uint4*)o = *(const uint4*)&res[0];

    // fused channel-mean partial: quad-reduce (lanes t, t^1, t^2 share px)
    psum += __shfl_xor(psum, 1);
    psum += __shfl_xor(psum, 2);
    if (csub == 0)
        atomicAdd(&smean[(size_t)(b * HW) + (size_t)r * W + w0 + px], psum * (1.f / C));
}

// ---------------------------------------------------------------------------
// windowed attention via MFMA. One wave per (b, head, wy, wx) window.
// q,k,v: NHWC bf16.  out: NHWC bf16.  setprio(1) around MFMA clusters (T5).
// ---------------------------------------------------------------------------
__global__ __launch_bounds__(64) void attn_k(
    const unsigned short* __restrict__ q, const unsigned short* __restrict__ k,
    const unsigned short* __restrict__ v, const float* __restrict__ si,
    const float* __restrict__ sn, const float* __restrict__ temp,
    unsigned short* __restrict__ out)
{
    __shared__ unsigned short Pl[64][72];   // P rows: pitch 144B (16B aligned)
    __shared__ unsigned short Vt[32][72];   // V^T rows: [d][kpix]

    const int id   = blockIdx.x;
    const int wx   = id & 31;
    const int wy   = (id >> 5) & 31;
    const int head = (id >> 10) & 7;
    const int b    = id >> 13;
    const int l    = threadIdx.x;
    const int pl15 = l & 15;
    const int g    = l >> 4;
    const int ch0  = head * 32;
    const int base = wy * 8 * W + wx * 8;       // window origin pixel
    const size_t bb = (size_t)b * HW;

    // ---- load Q/K fragments (A-frag layout: row=lane&15, kgrp=lane>>4) ----
    uint4 qv[4], kv[4];
    float qss[4], kss[4];
#pragma unroll
    for (int i = 0; i < 4; i++) {
        const int p = i * 16 + pl15;
        const size_t a = (bb + base + (p >> 3) * W + (p & 7)) * C + ch0 + g * 8;
        qv[i] = *(const uint4*)(q + a);
        kv[i] = *(const uint4*)(k + a);
        // partial squared norms over this lane's 8 channels
        float s0 = 0.f, s1 = 0.f;
        {
            uint4 u = qv[i];
            float f;
            f = bflo(u.x); s0 = fmaf(f, f, s0);  f = bfhi(u.x); s0 = fmaf(f, f, s0);
            f = bflo(u.y); s0 = fmaf(f, f, s0);  f = bfhi(u.y); s0 = fmaf(f, f, s0);
            f = bflo(u.z); s0 = fmaf(f, f, s0);  f = bfhi(u.z); s0 = fmaf(f, f, s0);
            f = bflo(u.w); s0 = fmaf(f, f, s0);  f = bfhi(u.w); s0 = fmaf(f, f, s0);
        }
        {
            uint4 u = kv[i];
            float f;
            f = bflo(u.x); s1 = fmaf(f, f, s1);  f = bfhi(u.x); s1 = fmaf(f, f, s1);
            f = bflo(u.y); s1 = fmaf(f, f, s1);  f = bfhi(u.y); s1 = fmaf(f, f, s1);
            f = bflo(u.z); s1 = fmaf(f, f, s1);  f = bfhi(u.z); s1 = fmaf(f, f, s1);
            f = bflo(u.w); s1 = fmaf(f, f, s1);  f = bfhi(u.w); s1 = fmaf(f, f, s1);
        }
        // full 32-ch norms: combine the 4 d-groups (lanes l, l^16, l^32, l^48)
        s0 += __shfl_xor(s0, 16); s0 += __shfl_xor(s0, 32);
        s1 += __shfl_xor(s1, 16); s1 += __shfl_xor(s1, 32);
        qss[i] = s0; kss[i] = s1;
    }

    // ---- stage V^T into LDS: lane l owns window pixel l (32 scalar writes) ----
    {
        const size_t a = (bb + base + (l >> 3) * W + (l & 7)) * C + ch0;
        const uint4* vp = (const uint4*)(v + a);
#pragma unroll
        for (int i = 0; i < 4; i++) {
            uint4 vv = vp[i];
            Vt[i * 8 + 0][l] = (unsigned short)(vv.x);
            Vt[i * 8 + 1][l] = (unsigned short)(vv.x >> 16);
            Vt[i * 8 + 2][l] = (unsigned short)(vv.y);
            Vt[i * 8 + 3][l] = (unsigned short)(vv.y >> 16);
            Vt[i * 8 + 4][l] = (unsigned short)(vv.z);
            Vt[i * 8 + 5][l] = (unsigned short)(vv.z >> 16);
            Vt[i * 8 + 6][l] = (unsigned short)(vv.w);
            Vt[i * 8 + 7][l] = (unsigned short)(vv.w >> 16);
        }
    }

    // ---- per-pixel scales ----
    const float tsc = temp[head] * 0.17677669529663689f;   // 32^-0.5
    float qmul[4], kscl[4];
#pragma unroll
    for (int i = 0; i < 4; i++) {
        const int p = i * 16 + pl15;
        const size_t pg = bb + base + (p >> 3) * W + (p & 7);
        const float il = si[pg];
        const float nz = sn[pg];
        qmul[i] = (1.f + il) * tsc / fmaxf(sqrtf(qss[i]), 1e-12f);
        kscl[i] = fminf(fmaxf(1.f - nz, 0.f), 1.f) / fmaxf(sqrtf(kss[i]), 1e-12f);
    }

    // ---- S = Q * K^T: 16 MFMAs ----
    f32x4 acc[4][4];
    __builtin_amdgcn_s_setprio(1);
#pragma unroll
    for (int qi = 0; qi < 4; qi++)
#pragma unroll
        for (int kj = 0; kj < 4; kj++)
            acc[qi][kj] = __builtin_amdgcn_mfma_f32_16x16x32_bf16(
                u2b(qv[qi]), u2b(kv[kj]), (f32x4){0.f, 0.f, 0.f, 0.f}, 0, 0, 0);
    __builtin_amdgcn_s_setprio(0);

    // ---- scale + softmax (rows owned: q = qi*16 + g*4 + rg) + P -> LDS ----
    float inv[4][4];
#pragma unroll
    for (int qi = 0; qi < 4; qi++) {
#pragma unroll
        for (int rg = 0; rg < 4; rg++) {
            const float qm = __shfl(qmul[qi], (g << 2) + rg);
            float s[4];
#pragma unroll
            for (int kj = 0; kj < 4; kj++) s[kj] = acc[qi][kj][rg] * kscl[kj] * qm;
            float mx = fmaxf(fmaxf(s[0], s[1]), fmaxf(s[2], s[3]));
            mx = fmaxf(mx, __shfl_xor(mx, 1));
            mx = fmaxf(mx, __shfl_xor(mx, 2));
            mx = fmaxf(mx, __shfl_xor(mx, 4));
            mx = fmaxf(mx, __shfl_xor(mx, 8));
            float sum = 0.f;
#pragma unroll
            for (int kj = 0; kj < 4; kj++) {
                const float e = __expf(s[kj] - mx);
                acc[qi][kj][rg] = e;
                sum += e;
            }
            sum += __shfl_xor(sum, 1);
            sum += __shfl_xor(sum, 2);
            sum += __shfl_xor(sum, 4);
            sum += __shfl_xor(sum, 8);
            inv[qi][rg] = 1.f / sum;
            const int qrow = qi * 16 + (g << 2) + rg;
#pragma unroll
            for (int kj = 0; kj < 4; kj++)
                Pl[qrow][pl15 + 16 * kj] = f2bf(acc[qi][kj][rg]);
        }
    }

    // ---- O = P * V: 16 MFMAs (K-dim = 64 k-pixels, 2 chunks of 32) ----
    f32x4 oacc[4][2];
#pragma unroll
    for (int qi = 0; qi < 4; qi++)
#pragma unroll
        for (int dj = 0; dj < 2; dj++) oacc[qi][dj] = (f32x4){0.f, 0.f, 0.f, 0.f};

#pragma unroll
    for (int kc = 0; kc < 2; kc++) {
        const bf16x8 vb0 = *(const bf16x8*)&Vt[pl15][kc * 32 + g * 8];
        const bf16x8 vb1 = *(const bf16x8*)&Vt[pl15 + 16][kc * 32 + g * 8];
        __builtin_amdgcn_s_setprio(1);
#pragma unroll
        for (int qi = 0; qi < 4; qi++) {
            const bf16x8 pa = *(const bf16x8*)&Pl[qi * 16 + pl15][kc * 32 + g * 8];
            oacc[qi][0] = __builtin_amdgcn_mfma_f32_16x16x32_bf16(pa, vb0, oacc[qi][0], 0, 0, 0);
            oacc[qi][1] = __builtin_amdgcn_mfma_f32_16x16x32_bf16(pa, vb1, oacc[qi][1], 0, 0, 0);
        }
        __builtin_amdgcn_s_setprio(0);
    }

    // ---- epilogue: row q = qi*16 + g*4 + rg, col d = pl15 + 16*dj ----
#pragma unroll
    for (int qi = 0; qi < 4; qi++) {
#pragma unroll
        for (int rg = 0; rg < 4; rg++) {
            const int qrow = qi * 16 + (g << 2) + rg;
            const size_t oaddr = (bb + base + (qrow >> 3) * W + (qrow & 7)) * C + ch0;
            const float sc = inv[qi][rg];
            out[oaddr + pl15]      = f2bf(oacc[qi][0][rg] * sc);
            out[oaddr + 16 + pl15] = f2bf(oacc[qi][1][rg] * sc);
        }
    }
}

// ---------------------------------------------------------------------------
extern "C" void kernel_launch(void* const* d_in, const int* in_sizes, int n_in,
                              void* d_out, int out_size, void* d_ws, size_t ws_size,
                              hipStream_t stream)
{
    const float* x        = (const float*)d_in[0];
    const float* w_iem    = (const float*)d_in[1];
    const float* g_iem    = (const float*)d_in[2];
    const float* b_iem    = (const float*)d_in[3];
    const float* w_nem    = (const float*)d_in[4];
    const float* g_nem    = (const float*)d_in[5];
    const float* b_nem    = (const float*)d_in[6];
    const float* w_iem_dw = (const float*)d_in[7];
    const float* w_nem_dw = (const float*)d_in[8];
    const float* w_q      = (const float*)d_in[9];
    const float* w_k      = (const float*)d_in[10];
    const float* w_v      = (const float*)d_in[11];
    const float* w_proj   = (const float*)d_in[12];
    const float* temp     = (const float*)d_in[13];

    // workspace carve-up (bytes)
    char* p = (char*)d_ws;
    unsigned short* zbuf = (unsigned short*)p;      p += 256;
    float* scl0 = (float*)p;                        p += 256 * 4;
    float* shf0 = (float*)p;                        p += 256 * 4;
    float* scl1 = (float*)p;                        p += 256 * 4;
    float* shf1 = (float*)p;                        p += 256 * 4;
    float* stats_part = (float*)p;                  p += (size_t)2048 * 512 * 4;  // 4MB
    float* sI  = (float*)p;                         p += (size_t)Bn * HW * 4;
    float* sN  = (float*)p;                         p += (size_t)Bn * HW * 4;
    unsigned short* Wp_iem = (unsigned short*)p;    p += 589824 * 2;
    unsigned short* Wp_nem = (unsigned short*)p;    p += 589824 * 2;
    unsigned short* Wpq = (unsigned short*)p;       p += 65536 * 2;
    unsigned short* Wpk = (unsigned short*)p;       p += 65536 * 2;
    unsigned short* Wpv = (unsigned short*)p;       p += 65536 * 2;
    unsigned short* Wpp = (unsigned short*)p;       p += 65536 * 2;
    unsigned short* xT   = (unsigned short*)p;      p += Bn * CHW * 2;  // NHWC bf16
    unsigned short* bufA = (unsigned short*)p;      p += Bn * CHW * 2;  // IEM raw (NHWC) / Q (NHWC)
    unsigned short* Ibf  = (unsigned short*)p;      p += Bn * CHW * 2;  // illum NHWC / attn out NHWC
    unsigned short* Nbf  = (unsigned short*)p;      p += Bn * CHW * 2;  // noise NHWC / V (NHWC)
    unsigned short* Obf  = (unsigned short*)p;      p += Bn * CHW * 2;  // NEM raw (NHWC) / K (NHWC)

    hipMemsetAsync(zbuf, 0, 256, stream);
    hipMemsetAsync(sI, 0, (size_t)Bn * HW * 4 * 2, stream);   // sI + sN contiguous

    packx_k<<<8192, 256, 0, stream>>>(x, xT);
    pack_k<<<2304, 256, 0, stream>>>(w_iem, Wp_iem, 9);
    pack_k<<<2304, 256, 0, stream>>>(w_nem, Wp_nem, 9);
    pack4_k<<<1024, 256, 0, stream>>>(w_q, w_k, w_v, w_proj, Wpq, Wpk, Wpv, Wpp);

    // fused IEM+NEM 3x3 conv (halo-shared B, NHWC out) + BN partials
    conv2_k<<<2048, 256, 0, stream>>>(xT, Wp_iem, Wp_nem, bufA, Obf, zbuf, stats_part);
    bn_reduce_k<<<512, 256, 0, stream>>>(stats_part, g_iem, b_iem, g_nem, b_nem,
                                         scl0, shf0, scl1, shf1);

    // merged depthwise (NHWC in/out; BN+relu6 on read, channel-mean on write)
    dwconv_k<<<32768, 256, 0, stream>>>(bufA, Obf, scl0, shf0, scl1, shf1,
                                        w_iem_dw, w_nem_dw, Ibf, Nbf, sI, sN);

    // fused Q+K projections -> NHWC bf16 (Q->bufA, K->Obf)
    gemm2_k<<<2048, 256, 0, stream>>>(Ibf, Nbf, Wpq, Wpk, bufA, Obf);
    // V projection (Nbf consumed by gemm2 above)
    gemm_k<false, true><<<2048, 256, 0, stream>>>(xT, Wpv, Nbf, nullptr);

    attn_k<<<16384, 64, 0, stream>>>(bufA, Obf, Nbf, sI, sN, temp, Ibf);

    // final projection -> fp32 d_out (NCHW)
    gemm_k<true, false><<<2048, 256, 0, stream>>>(Ibf, Wpp, nullptr, (float*)d_out);
}